// Round 14
// baseline (285.198 us; speedup 1.0000x reference)
//
#include <hip/hip_runtime.h>

#define N_NODES 100000
#define N_EDGES 1600000
#define DIM 64

#define NSLICE 8
#define SLICE_NODES ((N_NODES + NSLICE - 1) / NSLICE)     // 12500 nodes/slice

#define CAP 24                     // fixed slots/node (Poisson(16): ~3.4K ovf edges)
#define OVF_CAP 65536

// ---- legacy exact-CSR path constants (fallback) ----
#define SCAN_BLK 2048
#define NSCAN ((N_NODES + 1 + SCAN_BLK - 1) / SCAN_BLK)
#define SRT_CAP (N_EDGES + 4 * N_NODES)

// ===========================================================================
// Path A: fixed-cap bucket scatter (4-edge batched) + 2-stream pull
// ===========================================================================

__global__ void init_kernel(unsigned* __restrict__ cursor,
                            unsigned* __restrict__ ovf_cnt) {
    int i = blockIdx.x * blockDim.x + threadIdx.x;
    if (i < N_NODES) cursor[i] = 0u;
    if (i == 0) *ovf_cnt = 0u;
}

// XCD-sliced fixed-cap scatter. R8 config restored (scalar NONTEMPORAL
// streaming loads, grid 2048) + single change: 4 strided edges per
// iteration, phase-ordered so the 4 independent cursor atomics overlap
// instead of serializing. No LDS, ~30 VGPR -> high occupancy.
__global__ void scatter_fixed_kernel(const int* __restrict__ src,
                                     const int* __restrict__ dst,
                                     const float* __restrict__ w,
                                     unsigned* __restrict__ cursor,
                                     uint2* __restrict__ srt,
                                     unsigned* __restrict__ ovf_cnt,
                                     uint4* __restrict__ ovf) {
    int slice = blockIdx.x & (NSLICE - 1);
    int chunk = blockIdx.x >> 3;
    int nchunks = gridDim.x >> 3;
    int lo = slice * SLICE_NODES;
    int hi = lo + SLICE_NODES; if (hi > N_NODES) hi = N_NODES;
    int per = (N_EDGES + nchunks - 1) / nchunks;
    int e0 = chunk * per;
    int e1 = e0 + per; if (e1 > N_EDGES) e1 = N_EDGES;

    for (int e = e0 + (int)threadIdx.x; e < e1; e += 4 * 256) {
        int eA = e, eB = e + 256, eC = e + 512, eD = e + 768;
        // phase 1: dst loads (streaming, nontemporal)
        int dA = __builtin_nontemporal_load(&dst[eA]);
        int dB = (eB < e1) ? __builtin_nontemporal_load(&dst[eB]) : -1;
        int dC = (eC < e1) ? __builtin_nontemporal_load(&dst[eC]) : -1;
        int dD = (eD < e1) ? __builtin_nontemporal_load(&dst[eD]) : -1;
        bool mA = (dA >= lo && dA < hi);
        bool mB = (dB >= lo && dB < hi);
        bool mC = (dC >= lo && dC < hi);
        bool mD = (dD >= lo && dD < hi);
        // phase 2: src/w loads for hits (independent)
        int sA = 0, sB = 0, sC = 0, sD = 0;
        float wA = 0.f, wB = 0.f, wC = 0.f, wD = 0.f;
        if (mA) { sA = __builtin_nontemporal_load(&src[eA]);
                  wA = __builtin_nontemporal_load(&w[eA]); }
        if (mB) { sB = __builtin_nontemporal_load(&src[eB]);
                  wB = __builtin_nontemporal_load(&w[eB]); }
        if (mC) { sC = __builtin_nontemporal_load(&src[eC]);
                  wC = __builtin_nontemporal_load(&w[eC]); }
        if (mD) { sD = __builtin_nontemporal_load(&src[eD]);
                  wD = __builtin_nontemporal_load(&w[eD]); }
        // phase 3: independent cursor atomics (overlap in flight)
        unsigned pA = 0u, pB = 0u, pC = 0u, pD = 0u;
        if (mA) pA = atomicAdd(&cursor[dA], 1u);
        if (mB) pB = atomicAdd(&cursor[dB], 1u);
        if (mC) pC = atomicAdd(&cursor[dC], 1u);
        if (mD) pD = atomicAdd(&cursor[dD], 1u);
        // phase 4: stores / overflow
        if (mA) {
            if (pA < CAP) srt[(size_t)dA * CAP + pA] =
                make_uint2((unsigned)sA, __float_as_uint(wA));
            else {
                unsigned op = atomicAdd(ovf_cnt, 1u);
                if (op < OVF_CAP) ovf[op] =
                    make_uint4((unsigned)dA, (unsigned)sA, __float_as_uint(wA), 0u);
            }
        }
        if (mB) {
            if (pB < CAP) srt[(size_t)dB * CAP + pB] =
                make_uint2((unsigned)sB, __float_as_uint(wB));
            else {
                unsigned op = atomicAdd(ovf_cnt, 1u);
                if (op < OVF_CAP) ovf[op] =
                    make_uint4((unsigned)dB, (unsigned)sB, __float_as_uint(wB), 0u);
            }
        }
        if (mC) {
            if (pC < CAP) srt[(size_t)dC * CAP + pC] =
                make_uint2((unsigned)sC, __float_as_uint(wC));
            else {
                unsigned op = atomicAdd(ovf_cnt, 1u);
                if (op < OVF_CAP) ovf[op] =
                    make_uint4((unsigned)dC, (unsigned)sC, __float_as_uint(wC), 0u);
            }
        }
        if (mD) {
            if (pD < CAP) srt[(size_t)dD * CAP + pD] =
                make_uint2((unsigned)sD, __float_as_uint(wD));
            else {
                unsigned op = atomicAdd(ovf_cnt, 1u);
                if (op < OVF_CAP) ovf[op] =
                    make_uint4((unsigned)dD, (unsigned)sD, __float_as_uint(wD), 0u);
            }
        }
    }
}

// g = feat @ W — LDS-tiled, broadcast ds_read_b128, W column in VGPRs.
__global__ __launch_bounds__(256) void gemm_g_kernel(const float* __restrict__ feat,
                                                     const float* __restrict__ W,
                                                     float* __restrict__ g) {
    __shared__ float4 ft[64 * 16];   // 16 KB
    int tid = threadIdx.x, lane = tid & 63, wv = tid >> 6;

    float Wreg[DIM];
#pragma unroll
    for (int k = 0; k < DIM; ++k) Wreg[k] = W[k * DIM + lane];

    const float4* feat4 = (const float4*)feat;
    for (int tile = blockIdx.x; tile * 64 < N_NODES; tile += gridDim.x) {
        int base = tile * 64;
        int nrows = N_NODES - base; if (nrows > 64) nrows = 64;
        __syncthreads();
        for (int i = tid; i < 64 * 16; i += 256) {
            int r = i >> 4;
            ft[i] = (r < nrows) ? feat4[(size_t)(base + r) * 16 + (i & 15)]
                                : float4{0.f, 0.f, 0.f, 0.f};
        }
        __syncthreads();
        for (int r = wv; r < nrows; r += 4) {
            float acc = 0.f;
#pragma unroll
            for (int k4 = 0; k4 < 16; ++k4) {
                float4 f = ft[r * 16 + k4];   // uniform -> LDS broadcast
                acc = fmaf(f.x, Wreg[4 * k4 + 0], acc);
                acc = fmaf(f.y, Wreg[4 * k4 + 1], acc);
                acc = fmaf(f.z, Wreg[4 * k4 + 2], acc);
                acc = fmaf(f.w, Wreg[4 * k4 + 3], acc);
            }
            g[(size_t)(base + r) * DIM + lane] = acc;
        }
    }
}

// R12's proven pull (114-117 us): 2 strided node streams per wave, x4
// unroll, scalar selects for ragged tails, unconditional in-bounds loads.
__global__ __launch_bounds__(256) void pull_fixed_kernel(
        const float* __restrict__ g, const uint2* __restrict__ srt,
        const unsigned* __restrict__ cursor, const float* __restrict__ bias,
        float* __restrict__ out) {
    int tid = threadIdx.x, lane = tid & 63;
    float bv = bias[lane];
    int gw = (int)((blockIdx.x * blockDim.x + tid) >> 6);
    int nw = (int)((gridDim.x * blockDim.x) >> 6);

    for (int v = gw; v < N_NODES; v += 2 * nw) {
        int vB = v + nw;
        int cA = (int)__builtin_amdgcn_readfirstlane((int)cursor[v]);
        cA = cA < CAP ? cA : CAP;
        int cB = 0;
        if (vB < N_NODES) {
            cB = (int)__builtin_amdgcn_readfirstlane((int)cursor[vB]);
            cB = cB < CAP ? cB : CAP;
        }
        int vBc = vB < N_NODES ? vB : N_NODES - 1;
        const uint2* pA = srt + (size_t)v * CAP;
        const uint2* pB = srt + (size_t)vBc * CAP;

        float accA = 0.f, accB = 0.f;
        int kmax = cA > cB ? cA : cB;
        for (int k = 0; k < kmax; k += 4) {
#pragma unroll
            for (int j = 0; j < 4; ++j) {
                uint2 e = pA[k + j];                       // in-bounds (CAP slots)
                unsigned s = (k + j < cA) ? e.x : 0u;      // scalar selects
                float   ww = (k + j < cA) ? __uint_as_float(e.y) : 0.f;
                accA = fmaf(g[(size_t)s * DIM + lane], ww, accA);
            }
#pragma unroll
            for (int j = 0; j < 4; ++j) {
                uint2 e = pB[k + j];
                unsigned s = (k + j < cB) ? e.x : 0u;
                float   ww = (k + j < cB) ? __uint_as_float(e.y) : 0.f;
                accB = fmaf(g[(size_t)s * DIM + lane], ww, accB);
            }
        }
        __builtin_nontemporal_store(accA + bv, &out[(size_t)v * DIM + lane]);
        if (vB < N_NODES)
            __builtin_nontemporal_store(accB + bv, &out[(size_t)vB * DIM + lane]);
    }
}

// Apply rare overflow edges (pos >= CAP) after pull wrote out.
__global__ void cleanup_ovf_kernel(const float* __restrict__ g,
                                   const uint4* __restrict__ ovf,
                                   const unsigned* __restrict__ ovf_cnt,
                                   float* __restrict__ out) {
    int lane = threadIdx.x & 63;
    int wv = (int)((blockIdx.x * blockDim.x + threadIdx.x) >> 6);
    int nwv = (int)((gridDim.x * blockDim.x) >> 6);
    unsigned nraw = *ovf_cnt;
    int n = (int)(nraw < (unsigned)OVF_CAP ? nraw : (unsigned)OVF_CAP);
    for (int i = wv; i < n; i += nwv) {
        uint4 t = ovf[i];
        atomicAdd(&out[(size_t)t.x * DIM + lane],
                  g[(size_t)t.y * DIM + lane] * __uint_as_float(t.z));
    }
}

// ===========================================================================
// Path B (fallback): R7 exact padded-CSR pipeline
// ===========================================================================

__global__ void zero_u32(unsigned* __restrict__ p, int n) {
    int stride = gridDim.x * blockDim.x;
    for (int i = blockIdx.x * blockDim.x + threadIdx.x; i < n; i += stride)
        p[i] = 0u;
}

__global__ void hist_kernel(const int* __restrict__ dst, unsigned* __restrict__ cnt) {
    int slice = blockIdx.x & (NSLICE - 1);
    int chunk = blockIdx.x >> 3;
    int nchunks = gridDim.x >> 3;
    int lo = slice * SLICE_NODES;
    int hi = lo + SLICE_NODES; if (hi > N_NODES) hi = N_NODES;
    int per = (N_EDGES + nchunks - 1) / nchunks;
    int e0 = chunk * per;
    int e1 = e0 + per; if (e1 > N_EDGES) e1 = N_EDGES;
    for (int e = e0 + threadIdx.x; e < e1; e += blockDim.x) {
        int d = dst[e];
        if (d >= lo && d < hi) atomicAdd(&cnt[d], 1u);
    }
}

__global__ void scan1_kernel(const unsigned* __restrict__ cnt,
                             unsigned* __restrict__ off,
                             unsigned* __restrict__ partials) {
    __shared__ unsigned s[SCAN_BLK];
    int t = threadIdx.x;
    int base = blockIdx.x * SCAN_BLK;
    int i0 = base + t, i1 = base + t + 1024;
    unsigned c0 = (i0 < N_NODES) ? ((cnt[i0] + 3u) & ~3u) : 0u;
    unsigned c1 = (i1 < N_NODES) ? ((cnt[i1] + 3u) & ~3u) : 0u;
    s[t] = c0;
    s[t + 1024] = c1;
    __syncthreads();
    for (int o = 1; o < SCAN_BLK; o <<= 1) {
        unsigned a0 = s[t];
        unsigned a1 = s[t + 1024];
        unsigned b0 = (t >= o) ? s[t - o] : 0u;
        unsigned b1 = (t + 1024 >= o) ? s[t + 1024 - o] : 0u;
        __syncthreads();
        s[t] = a0 + b0;
        s[t + 1024] = a1 + b1;
        __syncthreads();
    }
    for (int i = t; i < SCAN_BLK; i += 1024) {
        int gg = base + i;
        if (gg <= N_NODES) off[gg] = (i == 0) ? 0u : s[i - 1];
    }
    if (t == 0) partials[blockIdx.x] = s[SCAN_BLK - 1];
}

__global__ void scan2_kernel(unsigned* __restrict__ partials) {
    int t = threadIdx.x;
    unsigned v = (t < NSCAN) ? partials[t] : 0u;
    unsigned orig = v;
    for (int o = 1; o < 64; o <<= 1) {
        unsigned n = __shfl_up(v, o, 64);
        if (t >= o) v += n;
    }
    if (t < NSCAN) partials[t] = v - orig;
}

__global__ void scan3_kernel(unsigned* __restrict__ off,
                             const unsigned* __restrict__ partials,
                             unsigned* __restrict__ cursor) {
    int i = blockIdx.x * blockDim.x + threadIdx.x;
    if (i <= N_NODES) {
        unsigned v = off[i] + partials[i / SCAN_BLK];
        off[i] = v;
        if (i < N_NODES) cursor[i] = v;
    }
}

__global__ void scatter_sort_kernel(const int* __restrict__ src,
                                    const int* __restrict__ dst,
                                    const float* __restrict__ w,
                                    unsigned* __restrict__ cursor,
                                    uint2* __restrict__ srt) {
    int slice = blockIdx.x & (NSLICE - 1);
    int chunk = blockIdx.x >> 3;
    int nchunks = gridDim.x >> 3;
    int lo = slice * SLICE_NODES;
    int hi = lo + SLICE_NODES; if (hi > N_NODES) hi = N_NODES;
    int per = (N_EDGES + nchunks - 1) / nchunks;
    int e0 = chunk * per;
    int e1 = e0 + per; if (e1 > N_EDGES) e1 = N_EDGES;
    for (int e = e0 + threadIdx.x; e < e1; e += blockDim.x) {
        int d = dst[e];
        if (d >= lo && d < hi) {
            unsigned pos = atomicAdd(&cursor[d], 1u);
            srt[pos] = make_uint2((unsigned)src[e], __float_as_uint(w[e]));
        }
    }
}

__global__ __launch_bounds__(256) void pull_scalar_kernel(
        const float* __restrict__ g, const uint2* __restrict__ srt,
        const unsigned* __restrict__ off, const float* __restrict__ bias,
        float* __restrict__ out) {
    int tid = threadIdx.x, lane = tid & 63;
    float bv = bias[lane];
    int gw = (int)((blockIdx.x * blockDim.x + tid) >> 6);
    int nw = (int)((gridDim.x * blockDim.x) >> 6);

    for (int v = gw; v < N_NODES; v += 2 * nw) {
        int vB = v + nw;
        int bA = (int)__builtin_amdgcn_readfirstlane((int)off[v]);
        int cA = (int)__builtin_amdgcn_readfirstlane((int)off[v + 1]) - bA;
        int bB = 0, cB = 0;
        if (vB < N_NODES) {
            bB = (int)__builtin_amdgcn_readfirstlane((int)off[vB]);
            cB = (int)__builtin_amdgcn_readfirstlane((int)off[vB + 1]) - bB;
        }
        float accA = 0.f, accB = 0.f;
        int kmax = cA > cB ? cA : cB;
        for (int k = 0; k < kmax; k += 4) {
            if (k < cA) {
                uint2 e0 = srt[bA + k + 0];
                uint2 e1 = srt[bA + k + 1];
                uint2 e2 = srt[bA + k + 2];
                uint2 e3 = srt[bA + k + 3];
                accA = fmaf(g[e0.x * DIM + lane], __uint_as_float(e0.y), accA);
                accA = fmaf(g[e1.x * DIM + lane], __uint_as_float(e1.y), accA);
                accA = fmaf(g[e2.x * DIM + lane], __uint_as_float(e2.y), accA);
                accA = fmaf(g[e3.x * DIM + lane], __uint_as_float(e3.y), accA);
            }
            if (k < cB) {
                uint2 e0 = srt[bB + k + 0];
                uint2 e1 = srt[bB + k + 1];
                uint2 e2 = srt[bB + k + 2];
                uint2 e3 = srt[bB + k + 3];
                accB = fmaf(g[e0.x * DIM + lane], __uint_as_float(e0.y), accB);
                accB = fmaf(g[e1.x * DIM + lane], __uint_as_float(e1.y), accB);
                accB = fmaf(g[e2.x * DIM + lane], __uint_as_float(e2.y), accB);
                accB = fmaf(g[e3.x * DIM + lane], __uint_as_float(e3.y), accB);
            }
        }
        out[(size_t)v * DIM + lane] = accA + bv;
        if (vB < N_NODES) out[(size_t)vB * DIM + lane] = accB + bv;
    }
}

// ===========================================================================
extern "C" void kernel_launch(void* const* d_in, const int* in_sizes, int n_in,
                              void* d_out, int out_size, void* d_ws, size_t ws_size,
                              hipStream_t stream) {
    const float* feat   = (const float*)d_in[0];
    const float* edge_w = (const float*)d_in[1];
    const int*   src    = (const int*)d_in[2];
    const int*   dst    = (const int*)d_in[3];
    const float* weight = (const float*)d_in[4];
    const float* bias   = (const float*)d_in[5];
    float* out = (float*)d_out;

    size_t g_sz    = (size_t)N_NODES * DIM * 4;              // 25.6 MB
    size_t srt_sz  = (size_t)N_NODES * CAP * 8;              // 19.2 MB
    size_t cur_sz  = (size_t)N_NODES * 4;                    // 0.4 MB
    size_t meta_sz = 64;                                     // ovf_cnt + pad
    size_t ovf_sz  = (size_t)OVF_CAP * 16;                   // 1 MB
    size_t neededA = g_sz + srt_sz + cur_sz + meta_sz + ovf_sz;   // ~46.2 MB

    size_t srtB_sz  = (size_t)SRT_CAP * 8;
    size_t metaB_sz = (size_t)N_NODES * 4 + (size_t)(N_NODES + 1) * 4
                    + (size_t)N_NODES * 4 + 64 * 4;

    if (ws_size >= neededA) {
        char* base = (char*)d_ws;
        float*    g       = (float*)base;
        uint2*    srt     = (uint2*)(base + g_sz);
        unsigned* cursor  = (unsigned*)(base + g_sz + srt_sz);
        unsigned* ovf_cnt = (unsigned*)(base + g_sz + srt_sz + cur_sz);
        uint4*    ovf     = (uint4*)(base + g_sz + srt_sz + cur_sz + meta_sz);

        init_kernel<<<(N_NODES + 255) / 256, 256, 0, stream>>>(cursor, ovf_cnt);
        scatter_fixed_kernel<<<2048, 256, 0, stream>>>(src, dst, edge_w,
                                                       cursor, srt, ovf_cnt, ovf);
        gemm_g_kernel<<<1563, 256, 0, stream>>>(feat, weight, g);
        pull_fixed_kernel<<<2048, 256, 0, stream>>>(g, srt, cursor, bias, out);
        cleanup_ovf_kernel<<<64, 256, 0, stream>>>(g, ovf, ovf_cnt, out);
    } else {
        // R7 exact padded-CSR path (proven)
        float*    g        = (float*)d_ws;
        uint2*    srt      = (uint2*)((char*)d_ws + g_sz);
        unsigned* cnt      = (unsigned*)((char*)d_ws + g_sz + srtB_sz);
        unsigned* off      = cnt + N_NODES;
        unsigned* cursor   = off + N_NODES + 1;
        unsigned* partials = cursor + N_NODES;

        zero_u32<<<(N_NODES + 255) / 256, 256, 0, stream>>>(cnt, N_NODES);
        zero_u32<<<2048, 256, 0, stream>>>((unsigned*)srt, SRT_CAP * 2);
        hist_kernel<<<2048, 256, 0, stream>>>(dst, cnt);
        scan1_kernel<<<NSCAN, 1024, 0, stream>>>(cnt, off, partials);
        scan2_kernel<<<1, 64, 0, stream>>>(partials);
        scan3_kernel<<<(N_NODES + 256) / 256, 256, 0, stream>>>(off, partials, cursor);
        scatter_sort_kernel<<<2048, 256, 0, stream>>>(src, dst, edge_w, cursor, srt);
        gemm_g_kernel<<<1563, 256, 0, stream>>>(feat, weight, g);
        pull_scalar_kernel<<<2048, 256, 0, stream>>>(g, srt, off, bias, out);
    }
}

// Round 15
// 277.217 us; speedup vs baseline: 1.0288x; 1.0288x over previous
//
#include <hip/hip_runtime.h>

#define N_NODES 100000
#define N_EDGES 1600000
#define DIM 64

#define NSLICE 8
#define SLICE_NODES ((N_NODES + NSLICE - 1) / NSLICE)     // 12500 nodes/slice

#define CAP 24                     // fixed slots/node (Poisson(16): ~3.4K ovf edges)
#define OVF_CAP 65536

// ---- legacy exact-CSR path constants (fallback) ----
#define SCAN_BLK 2048
#define NSCAN ((N_NODES + 1 + SCAN_BLK - 1) / SCAN_BLK)
#define SRT_CAP (N_EDGES + 4 * N_NODES)

__device__ __forceinline__ unsigned short f2bf(float f) {
    unsigned b = __float_as_uint(f);
    return (unsigned short)((b + 0x7FFFu + ((b >> 16) & 1u)) >> 16);  // RNE
}
__device__ __forceinline__ float bf2f(unsigned short u) {
    return __uint_as_float(((unsigned)u) << 16);
}

// ===========================================================================
// Path A: R8-exact scatter + bf16 g + R12 pull (dtype-only change)
// ===========================================================================

__global__ void init_kernel(unsigned* __restrict__ cursor,
                            unsigned* __restrict__ ovf_cnt) {
    int i = blockIdx.x * blockDim.x + threadIdx.x;
    if (i < N_NODES) cursor[i] = 0u;
    if (i == 0) *ovf_cnt = 0u;
}

// EXACT R8 scatter config: 1 edge/thread/iter, nontemporal streaming loads,
// grid 2048 (256 chunks x 8 slices). 8-VGPR class, no LDS -> high occupancy.
__global__ void scatter_fixed_kernel(const int* __restrict__ src,
                                     const int* __restrict__ dst,
                                     const float* __restrict__ w,
                                     unsigned* __restrict__ cursor,
                                     uint2* __restrict__ srt,
                                     unsigned* __restrict__ ovf_cnt,
                                     uint4* __restrict__ ovf) {
    int slice = blockIdx.x & (NSLICE - 1);
    int chunk = blockIdx.x >> 3;
    int nchunks = gridDim.x >> 3;
    int lo = slice * SLICE_NODES;
    int hi = lo + SLICE_NODES; if (hi > N_NODES) hi = N_NODES;
    int per = (N_EDGES + nchunks - 1) / nchunks;
    int e0 = chunk * per;
    int e1 = e0 + per; if (e1 > N_EDGES) e1 = N_EDGES;
    for (int e = e0 + threadIdx.x; e < e1; e += blockDim.x) {
        int d = __builtin_nontemporal_load(&dst[e]);
        if (d >= lo && d < hi) {
            int s = __builtin_nontemporal_load(&src[e]);
            float ww = __builtin_nontemporal_load(&w[e]);
            unsigned pos = atomicAdd(&cursor[d], 1u);
            if (pos < CAP) {
                srt[(size_t)d * CAP + pos] =
                    make_uint2((unsigned)s, __float_as_uint(ww));
            } else {
                unsigned op = atomicAdd(ovf_cnt, 1u);
                if (op < OVF_CAP)
                    ovf[op] = make_uint4((unsigned)d, (unsigned)s,
                                         __float_as_uint(ww), 0u);
            }
        }
    }
}

// g = feat @ W, stored BF16 (halves the pull's gather traffic).
__global__ __launch_bounds__(256) void gemm_g_bf16_kernel(
        const float* __restrict__ feat, const float* __restrict__ W,
        unsigned short* __restrict__ g) {
    __shared__ float4 ft[64 * 16];   // 16 KB
    int tid = threadIdx.x, lane = tid & 63, wv = tid >> 6;

    float Wreg[DIM];
#pragma unroll
    for (int k = 0; k < DIM; ++k) Wreg[k] = W[k * DIM + lane];

    const float4* feat4 = (const float4*)feat;
    for (int tile = blockIdx.x; tile * 64 < N_NODES; tile += gridDim.x) {
        int base = tile * 64;
        int nrows = N_NODES - base; if (nrows > 64) nrows = 64;
        __syncthreads();
        for (int i = tid; i < 64 * 16; i += 256) {
            int r = i >> 4;
            ft[i] = (r < nrows) ? feat4[(size_t)(base + r) * 16 + (i & 15)]
                                : float4{0.f, 0.f, 0.f, 0.f};
        }
        __syncthreads();
        for (int r = wv; r < nrows; r += 4) {
            float acc = 0.f;
#pragma unroll
            for (int k4 = 0; k4 < 16; ++k4) {
                float4 f = ft[r * 16 + k4];   // uniform -> LDS broadcast
                acc = fmaf(f.x, Wreg[4 * k4 + 0], acc);
                acc = fmaf(f.y, Wreg[4 * k4 + 1], acc);
                acc = fmaf(f.z, Wreg[4 * k4 + 2], acc);
                acc = fmaf(f.w, Wreg[4 * k4 + 3], acc);
            }
            g[(size_t)(base + r) * DIM + lane] = f2bf(acc);
        }
    }
}

// R12's proven pull structure, g now bf16 (128B gather lines instead of 256B).
__global__ __launch_bounds__(256) void pull_fixed_kernel(
        const unsigned short* __restrict__ g, const uint2* __restrict__ srt,
        const unsigned* __restrict__ cursor, const float* __restrict__ bias,
        float* __restrict__ out) {
    int tid = threadIdx.x, lane = tid & 63;
    float bv = bias[lane];
    int gw = (int)((blockIdx.x * blockDim.x + tid) >> 6);
    int nw = (int)((gridDim.x * blockDim.x) >> 6);

    for (int v = gw; v < N_NODES; v += 2 * nw) {
        int vB = v + nw;
        int cA = (int)__builtin_amdgcn_readfirstlane((int)cursor[v]);
        cA = cA < CAP ? cA : CAP;
        int cB = 0;
        if (vB < N_NODES) {
            cB = (int)__builtin_amdgcn_readfirstlane((int)cursor[vB]);
            cB = cB < CAP ? cB : CAP;
        }
        int vBc = vB < N_NODES ? vB : N_NODES - 1;
        const uint2* pA = srt + (size_t)v * CAP;
        const uint2* pB = srt + (size_t)vBc * CAP;

        float accA = 0.f, accB = 0.f;
        int kmax = cA > cB ? cA : cB;
        for (int k = 0; k < kmax; k += 4) {
#pragma unroll
            for (int j = 0; j < 4; ++j) {
                uint2 e = pA[k + j];                       // in-bounds (CAP slots)
                unsigned s = (k + j < cA) ? e.x : 0u;      // scalar selects
                float   ww = (k + j < cA) ? __uint_as_float(e.y) : 0.f;
                accA = fmaf(bf2f(g[(size_t)s * DIM + lane]), ww, accA);
            }
#pragma unroll
            for (int j = 0; j < 4; ++j) {
                uint2 e = pB[k + j];
                unsigned s = (k + j < cB) ? e.x : 0u;
                float   ww = (k + j < cB) ? __uint_as_float(e.y) : 0.f;
                accB = fmaf(bf2f(g[(size_t)s * DIM + lane]), ww, accB);
            }
        }
        __builtin_nontemporal_store(accA + bv, &out[(size_t)v * DIM + lane]);
        if (vB < N_NODES)
            __builtin_nontemporal_store(accB + bv, &out[(size_t)vB * DIM + lane]);
    }
}

// Apply rare overflow edges (pos >= CAP) after pull wrote out.
__global__ void cleanup_ovf_kernel(const unsigned short* __restrict__ g,
                                   const uint4* __restrict__ ovf,
                                   const unsigned* __restrict__ ovf_cnt,
                                   float* __restrict__ out) {
    int lane = threadIdx.x & 63;
    int wv = (int)((blockIdx.x * blockDim.x + threadIdx.x) >> 6);
    int nwv = (int)((gridDim.x * blockDim.x) >> 6);
    unsigned nraw = *ovf_cnt;
    int n = (int)(nraw < (unsigned)OVF_CAP ? nraw : (unsigned)OVF_CAP);
    for (int i = wv; i < n; i += nwv) {
        uint4 t = ovf[i];
        atomicAdd(&out[(size_t)t.x * DIM + lane],
                  bf2f(g[(size_t)t.y * DIM + lane]) * __uint_as_float(t.z));
    }
}

// ===========================================================================
// Path B (fallback): R7 exact padded-CSR pipeline (fp32 g)
// ===========================================================================

__global__ void zero_u32(unsigned* __restrict__ p, int n) {
    int stride = gridDim.x * blockDim.x;
    for (int i = blockIdx.x * blockDim.x + threadIdx.x; i < n; i += stride)
        p[i] = 0u;
}

__global__ __launch_bounds__(256) void gemm_g_kernel(const float* __restrict__ feat,
                                                     const float* __restrict__ W,
                                                     float* __restrict__ g) {
    __shared__ float4 ft[64 * 16];
    int tid = threadIdx.x, lane = tid & 63, wv = tid >> 6;
    float Wreg[DIM];
#pragma unroll
    for (int k = 0; k < DIM; ++k) Wreg[k] = W[k * DIM + lane];
    const float4* feat4 = (const float4*)feat;
    for (int tile = blockIdx.x; tile * 64 < N_NODES; tile += gridDim.x) {
        int base = tile * 64;
        int nrows = N_NODES - base; if (nrows > 64) nrows = 64;
        __syncthreads();
        for (int i = tid; i < 64 * 16; i += 256) {
            int r = i >> 4;
            ft[i] = (r < nrows) ? feat4[(size_t)(base + r) * 16 + (i & 15)]
                                : float4{0.f, 0.f, 0.f, 0.f};
        }
        __syncthreads();
        for (int r = wv; r < nrows; r += 4) {
            float acc = 0.f;
#pragma unroll
            for (int k4 = 0; k4 < 16; ++k4) {
                float4 f = ft[r * 16 + k4];
                acc = fmaf(f.x, Wreg[4 * k4 + 0], acc);
                acc = fmaf(f.y, Wreg[4 * k4 + 1], acc);
                acc = fmaf(f.z, Wreg[4 * k4 + 2], acc);
                acc = fmaf(f.w, Wreg[4 * k4 + 3], acc);
            }
            g[(size_t)(base + r) * DIM + lane] = acc;
        }
    }
}

__global__ void hist_kernel(const int* __restrict__ dst, unsigned* __restrict__ cnt) {
    int slice = blockIdx.x & (NSLICE - 1);
    int chunk = blockIdx.x >> 3;
    int nchunks = gridDim.x >> 3;
    int lo = slice * SLICE_NODES;
    int hi = lo + SLICE_NODES; if (hi > N_NODES) hi = N_NODES;
    int per = (N_EDGES + nchunks - 1) / nchunks;
    int e0 = chunk * per;
    int e1 = e0 + per; if (e1 > N_EDGES) e1 = N_EDGES;
    for (int e = e0 + threadIdx.x; e < e1; e += blockDim.x) {
        int d = dst[e];
        if (d >= lo && d < hi) atomicAdd(&cnt[d], 1u);
    }
}

__global__ void scan1_kernel(const unsigned* __restrict__ cnt,
                             unsigned* __restrict__ off,
                             unsigned* __restrict__ partials) {
    __shared__ unsigned s[SCAN_BLK];
    int t = threadIdx.x;
    int base = blockIdx.x * SCAN_BLK;
    int i0 = base + t, i1 = base + t + 1024;
    unsigned c0 = (i0 < N_NODES) ? ((cnt[i0] + 3u) & ~3u) : 0u;
    unsigned c1 = (i1 < N_NODES) ? ((cnt[i1] + 3u) & ~3u) : 0u;
    s[t] = c0;
    s[t + 1024] = c1;
    __syncthreads();
    for (int o = 1; o < SCAN_BLK; o <<= 1) {
        unsigned a0 = s[t];
        unsigned a1 = s[t + 1024];
        unsigned b0 = (t >= o) ? s[t - o] : 0u;
        unsigned b1 = (t + 1024 >= o) ? s[t + 1024 - o] : 0u;
        __syncthreads();
        s[t] = a0 + b0;
        s[t + 1024] = a1 + b1;
        __syncthreads();
    }
    for (int i = t; i < SCAN_BLK; i += 1024) {
        int gg = base + i;
        if (gg <= N_NODES) off[gg] = (i == 0) ? 0u : s[i - 1];
    }
    if (t == 0) partials[blockIdx.x] = s[SCAN_BLK - 1];
}

__global__ void scan2_kernel(unsigned* __restrict__ partials) {
    int t = threadIdx.x;
    unsigned v = (t < NSCAN) ? partials[t] : 0u;
    unsigned orig = v;
    for (int o = 1; o < 64; o <<= 1) {
        unsigned n = __shfl_up(v, o, 64);
        if (t >= o) v += n;
    }
    if (t < NSCAN) partials[t] = v - orig;
}

__global__ void scan3_kernel(unsigned* __restrict__ off,
                             const unsigned* __restrict__ partials,
                             unsigned* __restrict__ cursor) {
    int i = blockIdx.x * blockDim.x + threadIdx.x;
    if (i <= N_NODES) {
        unsigned v = off[i] + partials[i / SCAN_BLK];
        off[i] = v;
        if (i < N_NODES) cursor[i] = v;
    }
}

__global__ void scatter_sort_kernel(const int* __restrict__ src,
                                    const int* __restrict__ dst,
                                    const float* __restrict__ w,
                                    unsigned* __restrict__ cursor,
                                    uint2* __restrict__ srt) {
    int slice = blockIdx.x & (NSLICE - 1);
    int chunk = blockIdx.x >> 3;
    int nchunks = gridDim.x >> 3;
    int lo = slice * SLICE_NODES;
    int hi = lo + SLICE_NODES; if (hi > N_NODES) hi = N_NODES;
    int per = (N_EDGES + nchunks - 1) / nchunks;
    int e0 = chunk * per;
    int e1 = e0 + per; if (e1 > N_EDGES) e1 = N_EDGES;
    for (int e = e0 + threadIdx.x; e < e1; e += blockDim.x) {
        int d = dst[e];
        if (d >= lo && d < hi) {
            unsigned pos = atomicAdd(&cursor[d], 1u);
            srt[pos] = make_uint2((unsigned)src[e], __float_as_uint(w[e]));
        }
    }
}

__global__ __launch_bounds__(256) void pull_scalar_kernel(
        const float* __restrict__ g, const uint2* __restrict__ srt,
        const unsigned* __restrict__ off, const float* __restrict__ bias,
        float* __restrict__ out) {
    int tid = threadIdx.x, lane = tid & 63;
    float bv = bias[lane];
    int gw = (int)((blockIdx.x * blockDim.x + tid) >> 6);
    int nw = (int)((gridDim.x * blockDim.x) >> 6);

    for (int v = gw; v < N_NODES; v += 2 * nw) {
        int vB = v + nw;
        int bA = (int)__builtin_amdgcn_readfirstlane((int)off[v]);
        int cA = (int)__builtin_amdgcn_readfirstlane((int)off[v + 1]) - bA;
        int bB = 0, cB = 0;
        if (vB < N_NODES) {
            bB = (int)__builtin_amdgcn_readfirstlane((int)off[vB]);
            cB = (int)__builtin_amdgcn_readfirstlane((int)off[vB + 1]) - bB;
        }
        float accA = 0.f, accB = 0.f;
        int kmax = cA > cB ? cA : cB;
        for (int k = 0; k < kmax; k += 4) {
            if (k < cA) {
                uint2 e0 = srt[bA + k + 0];
                uint2 e1 = srt[bA + k + 1];
                uint2 e2 = srt[bA + k + 2];
                uint2 e3 = srt[bA + k + 3];
                accA = fmaf(g[e0.x * DIM + lane], __uint_as_float(e0.y), accA);
                accA = fmaf(g[e1.x * DIM + lane], __uint_as_float(e1.y), accA);
                accA = fmaf(g[e2.x * DIM + lane], __uint_as_float(e2.y), accA);
                accA = fmaf(g[e3.x * DIM + lane], __uint_as_float(e3.y), accA);
            }
            if (k < cB) {
                uint2 e0 = srt[bB + k + 0];
                uint2 e1 = srt[bB + k + 1];
                uint2 e2 = srt[bB + k + 2];
                uint2 e3 = srt[bB + k + 3];
                accB = fmaf(g[e0.x * DIM + lane], __uint_as_float(e0.y), accB);
                accB = fmaf(g[e1.x * DIM + lane], __uint_as_float(e1.y), accB);
                accB = fmaf(g[e2.x * DIM + lane], __uint_as_float(e2.y), accB);
                accB = fmaf(g[e3.x * DIM + lane], __uint_as_float(e3.y), accB);
            }
        }
        out[(size_t)v * DIM + lane] = accA + bv;
        if (vB < N_NODES) out[(size_t)vB * DIM + lane] = accB + bv;
    }
}

// ===========================================================================
extern "C" void kernel_launch(void* const* d_in, const int* in_sizes, int n_in,
                              void* d_out, int out_size, void* d_ws, size_t ws_size,
                              hipStream_t stream) {
    const float* feat   = (const float*)d_in[0];
    const float* edge_w = (const float*)d_in[1];
    const int*   src    = (const int*)d_in[2];
    const int*   dst    = (const int*)d_in[3];
    const float* weight = (const float*)d_in[4];
    const float* bias   = (const float*)d_in[5];
    float* out = (float*)d_out;

    size_t gb_sz   = (size_t)N_NODES * DIM * 2;              // 12.8 MB (bf16)
    gb_sz = (gb_sz + 255) & ~(size_t)255;
    size_t srt_sz  = (size_t)N_NODES * CAP * 8;              // 19.2 MB
    size_t cur_sz  = (size_t)N_NODES * 4;                    // 0.4 MB
    size_t meta_sz = 64;
    size_t ovf_sz  = (size_t)OVF_CAP * 16;                   // 1 MB
    size_t neededA = gb_sz + srt_sz + cur_sz + meta_sz + ovf_sz;  // ~33.4 MB

    size_t g_sz    = (size_t)N_NODES * DIM * 4;
    size_t srtB_sz = (size_t)SRT_CAP * 8;

    if (ws_size >= neededA) {
        char* base = (char*)d_ws;
        unsigned short* g = (unsigned short*)base;
        uint2*    srt     = (uint2*)(base + gb_sz);
        unsigned* cursor  = (unsigned*)(base + gb_sz + srt_sz);
        unsigned* ovf_cnt = (unsigned*)(base + gb_sz + srt_sz + cur_sz);
        uint4*    ovf     = (uint4*)(base + gb_sz + srt_sz + cur_sz + meta_sz);

        init_kernel<<<(N_NODES + 255) / 256, 256, 0, stream>>>(cursor, ovf_cnt);
        scatter_fixed_kernel<<<2048, 256, 0, stream>>>(src, dst, edge_w,
                                                       cursor, srt, ovf_cnt, ovf);
        gemm_g_bf16_kernel<<<1563, 256, 0, stream>>>(feat, weight, g);
        pull_fixed_kernel<<<2048, 256, 0, stream>>>(g, srt, cursor, bias, out);
        cleanup_ovf_kernel<<<64, 256, 0, stream>>>(g, ovf, ovf_cnt, out);
    } else {
        // R7 exact padded-CSR path (proven, fp32 g)
        float*    g        = (float*)d_ws;
        uint2*    srt      = (uint2*)((char*)d_ws + g_sz);
        unsigned* cnt      = (unsigned*)((char*)d_ws + g_sz + srtB_sz);
        unsigned* off      = cnt + N_NODES;
        unsigned* cursor   = off + N_NODES + 1;
        unsigned* partials = cursor + N_NODES;

        zero_u32<<<(N_NODES + 255) / 256, 256, 0, stream>>>(cnt, N_NODES);
        zero_u32<<<2048, 256, 0, stream>>>((unsigned*)srt, SRT_CAP * 2);
        hist_kernel<<<2048, 256, 0, stream>>>(dst, cnt);
        scan1_kernel<<<NSCAN, 1024, 0, stream>>>(cnt, off, partials);
        scan2_kernel<<<1, 64, 0, stream>>>(partials);
        scan3_kernel<<<(N_NODES + 256) / 256, 256, 0, stream>>>(off, partials, cursor);
        scatter_sort_kernel<<<2048, 256, 0, stream>>>(src, dst, edge_w, cursor, srt);
        gemm_g_kernel<<<1563, 256, 0, stream>>>(feat, weight, g);
        pull_scalar_kernel<<<2048, 256, 0, stream>>>(g, srt, off, bias, out);
    }
}

// Round 16
// 225.749 us; speedup vs baseline: 1.2633x; 1.2280x over previous
//
#include <hip/hip_runtime.h>

#define N_NODES 100000
#define N_EDGES 1600000
#define DIM 64

#define NSLICE 8
#define SLICE_NODES ((N_NODES + NSLICE - 1) / NSLICE)     // 12500 nodes/slice

#define CAP 32                     // 256B-aligned node rows (R8-proven); ~200 ovf edges
#define OVF_CAP 65536

// ---- legacy exact-CSR path constants (fallback) ----
#define SCAN_BLK 2048
#define NSCAN ((N_NODES + 1 + SCAN_BLK - 1) / SCAN_BLK)
#define SRT_CAP (N_EDGES + 4 * N_NODES)

__device__ __forceinline__ unsigned short f2bf(float f) {
    unsigned b = __float_as_uint(f);
    return (unsigned short)((b + 0x7FFFu + ((b >> 16) & 1u)) >> 16);  // RNE
}
__device__ __forceinline__ float bf2f(unsigned short u) {
    return __uint_as_float(((unsigned)u) << 16);
}

// ===========================================================================
// Path A: R8-exact scatter (CAP=32) + bf16 g + R12 pull
// ===========================================================================

__global__ void init_kernel(unsigned* __restrict__ cursor,
                            unsigned* __restrict__ ovf_cnt) {
    int i = blockIdx.x * blockDim.x + threadIdx.x;
    if (i < N_NODES) cursor[i] = 0u;
    if (i == 0) *ovf_cnt = 0u;
}

// EXACT R8 scatter config: 1 edge/thread/iter, nontemporal streaming loads,
// grid 2048 (256 chunks x 8 slices), CAP=32 so each node row = 2 full
// 128B lines (dense whole-line fills, minimal partial writebacks).
__global__ void scatter_fixed_kernel(const int* __restrict__ src,
                                     const int* __restrict__ dst,
                                     const float* __restrict__ w,
                                     unsigned* __restrict__ cursor,
                                     uint2* __restrict__ srt,
                                     unsigned* __restrict__ ovf_cnt,
                                     uint4* __restrict__ ovf) {
    int slice = blockIdx.x & (NSLICE - 1);
    int chunk = blockIdx.x >> 3;
    int nchunks = gridDim.x >> 3;
    int lo = slice * SLICE_NODES;
    int hi = lo + SLICE_NODES; if (hi > N_NODES) hi = N_NODES;
    int per = (N_EDGES + nchunks - 1) / nchunks;
    int e0 = chunk * per;
    int e1 = e0 + per; if (e1 > N_EDGES) e1 = N_EDGES;
    for (int e = e0 + threadIdx.x; e < e1; e += blockDim.x) {
        int d = __builtin_nontemporal_load(&dst[e]);
        if (d >= lo && d < hi) {
            int s = __builtin_nontemporal_load(&src[e]);
            float ww = __builtin_nontemporal_load(&w[e]);
            unsigned pos = atomicAdd(&cursor[d], 1u);
            if (pos < CAP) {
                srt[(size_t)d * CAP + pos] =
                    make_uint2((unsigned)s, __float_as_uint(ww));
            } else {
                unsigned op = atomicAdd(ovf_cnt, 1u);
                if (op < OVF_CAP)
                    ovf[op] = make_uint4((unsigned)d, (unsigned)s,
                                         __float_as_uint(ww), 0u);
            }
        }
    }
}

// g = feat @ W, stored BF16 (halves the pull's gather traffic).
__global__ __launch_bounds__(256) void gemm_g_bf16_kernel(
        const float* __restrict__ feat, const float* __restrict__ W,
        unsigned short* __restrict__ g) {
    __shared__ float4 ft[64 * 16];   // 16 KB
    int tid = threadIdx.x, lane = tid & 63, wv = tid >> 6;

    float Wreg[DIM];
#pragma unroll
    for (int k = 0; k < DIM; ++k) Wreg[k] = W[k * DIM + lane];

    const float4* feat4 = (const float4*)feat;
    for (int tile = blockIdx.x; tile * 64 < N_NODES; tile += gridDim.x) {
        int base = tile * 64;
        int nrows = N_NODES - base; if (nrows > 64) nrows = 64;
        __syncthreads();
        for (int i = tid; i < 64 * 16; i += 256) {
            int r = i >> 4;
            ft[i] = (r < nrows) ? feat4[(size_t)(base + r) * 16 + (i & 15)]
                                : float4{0.f, 0.f, 0.f, 0.f};
        }
        __syncthreads();
        for (int r = wv; r < nrows; r += 4) {
            float acc = 0.f;
#pragma unroll
            for (int k4 = 0; k4 < 16; ++k4) {
                float4 f = ft[r * 16 + k4];   // uniform -> LDS broadcast
                acc = fmaf(f.x, Wreg[4 * k4 + 0], acc);
                acc = fmaf(f.y, Wreg[4 * k4 + 1], acc);
                acc = fmaf(f.z, Wreg[4 * k4 + 2], acc);
                acc = fmaf(f.w, Wreg[4 * k4 + 3], acc);
            }
            g[(size_t)(base + r) * DIM + lane] = f2bf(acc);
        }
    }
}

// R12's proven pull structure, bf16 g (128B gather lines).
__global__ __launch_bounds__(256) void pull_fixed_kernel(
        const unsigned short* __restrict__ g, const uint2* __restrict__ srt,
        const unsigned* __restrict__ cursor, const float* __restrict__ bias,
        float* __restrict__ out) {
    int tid = threadIdx.x, lane = tid & 63;
    float bv = bias[lane];
    int gw = (int)((blockIdx.x * blockDim.x + tid) >> 6);
    int nw = (int)((gridDim.x * blockDim.x) >> 6);

    for (int v = gw; v < N_NODES; v += 2 * nw) {
        int vB = v + nw;
        int cA = (int)__builtin_amdgcn_readfirstlane((int)cursor[v]);
        cA = cA < CAP ? cA : CAP;
        int cB = 0;
        if (vB < N_NODES) {
            cB = (int)__builtin_amdgcn_readfirstlane((int)cursor[vB]);
            cB = cB < CAP ? cB : CAP;
        }
        int vBc = vB < N_NODES ? vB : N_NODES - 1;
        const uint2* pA = srt + (size_t)v * CAP;
        const uint2* pB = srt + (size_t)vBc * CAP;

        float accA = 0.f, accB = 0.f;
        int kmax = cA > cB ? cA : cB;
        for (int k = 0; k < kmax; k += 4) {
#pragma unroll
            for (int j = 0; j < 4; ++j) {
                uint2 e = pA[k + j];                       // in-bounds (CAP slots)
                unsigned s = (k + j < cA) ? e.x : 0u;      // scalar selects
                float   ww = (k + j < cA) ? __uint_as_float(e.y) : 0.f;
                accA = fmaf(bf2f(g[(size_t)s * DIM + lane]), ww, accA);
            }
#pragma unroll
            for (int j = 0; j < 4; ++j) {
                uint2 e = pB[k + j];
                unsigned s = (k + j < cB) ? e.x : 0u;
                float   ww = (k + j < cB) ? __uint_as_float(e.y) : 0.f;
                accB = fmaf(bf2f(g[(size_t)s * DIM + lane]), ww, accB);
            }
        }
        __builtin_nontemporal_store(accA + bv, &out[(size_t)v * DIM + lane]);
        if (vB < N_NODES)
            __builtin_nontemporal_store(accB + bv, &out[(size_t)vB * DIM + lane]);
    }
}

// Apply rare overflow edges (pos >= CAP) after pull wrote out.
__global__ void cleanup_ovf_kernel(const unsigned short* __restrict__ g,
                                   const uint4* __restrict__ ovf,
                                   const unsigned* __restrict__ ovf_cnt,
                                   float* __restrict__ out) {
    int lane = threadIdx.x & 63;
    int wv = (int)((blockIdx.x * blockDim.x + threadIdx.x) >> 6);
    int nwv = (int)((gridDim.x * blockDim.x) >> 6);
    unsigned nraw = *ovf_cnt;
    int n = (int)(nraw < (unsigned)OVF_CAP ? nraw : (unsigned)OVF_CAP);
    for (int i = wv; i < n; i += nwv) {
        uint4 t = ovf[i];
        atomicAdd(&out[(size_t)t.x * DIM + lane],
                  bf2f(g[(size_t)t.y * DIM + lane]) * __uint_as_float(t.z));
    }
}

// ===========================================================================
// Path B (fallback): R7 exact padded-CSR pipeline (fp32 g)
// ===========================================================================

__global__ void zero_u32(unsigned* __restrict__ p, int n) {
    int stride = gridDim.x * blockDim.x;
    for (int i = blockIdx.x * blockDim.x + threadIdx.x; i < n; i += stride)
        p[i] = 0u;
}

__global__ __launch_bounds__(256) void gemm_g_kernel(const float* __restrict__ feat,
                                                     const float* __restrict__ W,
                                                     float* __restrict__ g) {
    __shared__ float4 ft[64 * 16];
    int tid = threadIdx.x, lane = tid & 63, wv = tid >> 6;
    float Wreg[DIM];
#pragma unroll
    for (int k = 0; k < DIM; ++k) Wreg[k] = W[k * DIM + lane];
    const float4* feat4 = (const float4*)feat;
    for (int tile = blockIdx.x; tile * 64 < N_NODES; tile += gridDim.x) {
        int base = tile * 64;
        int nrows = N_NODES - base; if (nrows > 64) nrows = 64;
        __syncthreads();
        for (int i = tid; i < 64 * 16; i += 256) {
            int r = i >> 4;
            ft[i] = (r < nrows) ? feat4[(size_t)(base + r) * 16 + (i & 15)]
                                : float4{0.f, 0.f, 0.f, 0.f};
        }
        __syncthreads();
        for (int r = wv; r < nrows; r += 4) {
            float acc = 0.f;
#pragma unroll
            for (int k4 = 0; k4 < 16; ++k4) {
                float4 f = ft[r * 16 + k4];
                acc = fmaf(f.x, Wreg[4 * k4 + 0], acc);
                acc = fmaf(f.y, Wreg[4 * k4 + 1], acc);
                acc = fmaf(f.z, Wreg[4 * k4 + 2], acc);
                acc = fmaf(f.w, Wreg[4 * k4 + 3], acc);
            }
            g[(size_t)(base + r) * DIM + lane] = acc;
        }
    }
}

__global__ void hist_kernel(const int* __restrict__ dst, unsigned* __restrict__ cnt) {
    int slice = blockIdx.x & (NSLICE - 1);
    int chunk = blockIdx.x >> 3;
    int nchunks = gridDim.x >> 3;
    int lo = slice * SLICE_NODES;
    int hi = lo + SLICE_NODES; if (hi > N_NODES) hi = N_NODES;
    int per = (N_EDGES + nchunks - 1) / nchunks;
    int e0 = chunk * per;
    int e1 = e0 + per; if (e1 > N_EDGES) e1 = N_EDGES;
    for (int e = e0 + threadIdx.x; e < e1; e += blockDim.x) {
        int d = dst[e];
        if (d >= lo && d < hi) atomicAdd(&cnt[d], 1u);
    }
}

__global__ void scan1_kernel(const unsigned* __restrict__ cnt,
                             unsigned* __restrict__ off,
                             unsigned* __restrict__ partials) {
    __shared__ unsigned s[SCAN_BLK];
    int t = threadIdx.x;
    int base = blockIdx.x * SCAN_BLK;
    int i0 = base + t, i1 = base + t + 1024;
    unsigned c0 = (i0 < N_NODES) ? ((cnt[i0] + 3u) & ~3u) : 0u;
    unsigned c1 = (i1 < N_NODES) ? ((cnt[i1] + 3u) & ~3u) : 0u;
    s[t] = c0;
    s[t + 1024] = c1;
    __syncthreads();
    for (int o = 1; o < SCAN_BLK; o <<= 1) {
        unsigned a0 = s[t];
        unsigned a1 = s[t + 1024];
        unsigned b0 = (t >= o) ? s[t - o] : 0u;
        unsigned b1 = (t + 1024 >= o) ? s[t + 1024 - o] : 0u;
        __syncthreads();
        s[t] = a0 + b0;
        s[t + 1024] = a1 + b1;
        __syncthreads();
    }
    for (int i = t; i < SCAN_BLK; i += 1024) {
        int gg = base + i;
        if (gg <= N_NODES) off[gg] = (i == 0) ? 0u : s[i - 1];
    }
    if (t == 0) partials[blockIdx.x] = s[SCAN_BLK - 1];
}

__global__ void scan2_kernel(unsigned* __restrict__ partials) {
    int t = threadIdx.x;
    unsigned v = (t < NSCAN) ? partials[t] : 0u;
    unsigned orig = v;
    for (int o = 1; o < 64; o <<= 1) {
        unsigned n = __shfl_up(v, o, 64);
        if (t >= o) v += n;
    }
    if (t < NSCAN) partials[t] = v - orig;
}

__global__ void scan3_kernel(unsigned* __restrict__ off,
                             const unsigned* __restrict__ partials,
                             unsigned* __restrict__ cursor) {
    int i = blockIdx.x * blockDim.x + threadIdx.x;
    if (i <= N_NODES) {
        unsigned v = off[i] + partials[i / SCAN_BLK];
        off[i] = v;
        if (i < N_NODES) cursor[i] = v;
    }
}

__global__ void scatter_sort_kernel(const int* __restrict__ src,
                                    const int* __restrict__ dst,
                                    const float* __restrict__ w,
                                    unsigned* __restrict__ cursor,
                                    uint2* __restrict__ srt) {
    int slice = blockIdx.x & (NSLICE - 1);
    int chunk = blockIdx.x >> 3;
    int nchunks = gridDim.x >> 3;
    int lo = slice * SLICE_NODES;
    int hi = lo + SLICE_NODES; if (hi > N_NODES) hi = N_NODES;
    int per = (N_EDGES + nchunks - 1) / nchunks;
    int e0 = chunk * per;
    int e1 = e0 + per; if (e1 > N_EDGES) e1 = N_EDGES;
    for (int e = e0 + threadIdx.x; e < e1; e += blockDim.x) {
        int d = dst[e];
        if (d >= lo && d < hi) {
            unsigned pos = atomicAdd(&cursor[d], 1u);
            srt[pos] = make_uint2((unsigned)src[e], __float_as_uint(w[e]));
        }
    }
}

__global__ __launch_bounds__(256) void pull_scalar_kernel(
        const float* __restrict__ g, const uint2* __restrict__ srt,
        const unsigned* __restrict__ off, const float* __restrict__ bias,
        float* __restrict__ out) {
    int tid = threadIdx.x, lane = tid & 63;
    float bv = bias[lane];
    int gw = (int)((blockIdx.x * blockDim.x + tid) >> 6);
    int nw = (int)((gridDim.x * blockDim.x) >> 6);

    for (int v = gw; v < N_NODES; v += 2 * nw) {
        int vB = v + nw;
        int bA = (int)__builtin_amdgcn_readfirstlane((int)off[v]);
        int cA = (int)__builtin_amdgcn_readfirstlane((int)off[v + 1]) - bA;
        int bB = 0, cB = 0;
        if (vB < N_NODES) {
            bB = (int)__builtin_amdgcn_readfirstlane((int)off[vB]);
            cB = (int)__builtin_amdgcn_readfirstlane((int)off[vB + 1]) - bB;
        }
        float accA = 0.f, accB = 0.f;
        int kmax = cA > cB ? cA : cB;
        for (int k = 0; k < kmax; k += 4) {
            if (k < cA) {
                uint2 e0 = srt[bA + k + 0];
                uint2 e1 = srt[bA + k + 1];
                uint2 e2 = srt[bA + k + 2];
                uint2 e3 = srt[bA + k + 3];
                accA = fmaf(g[e0.x * DIM + lane], __uint_as_float(e0.y), accA);
                accA = fmaf(g[e1.x * DIM + lane], __uint_as_float(e1.y), accA);
                accA = fmaf(g[e2.x * DIM + lane], __uint_as_float(e2.y), accA);
                accA = fmaf(g[e3.x * DIM + lane], __uint_as_float(e3.y), accA);
            }
            if (k < cB) {
                uint2 e0 = srt[bB + k + 0];
                uint2 e1 = srt[bB + k + 1];
                uint2 e2 = srt[bB + k + 2];
                uint2 e3 = srt[bB + k + 3];
                accB = fmaf(g[e0.x * DIM + lane], __uint_as_float(e0.y), accB);
                accB = fmaf(g[e1.x * DIM + lane], __uint_as_float(e1.y), accB);
                accB = fmaf(g[e2.x * DIM + lane], __uint_as_float(e2.y), accB);
                accB = fmaf(g[e3.x * DIM + lane], __uint_as_float(e3.y), accB);
            }
        }
        out[(size_t)v * DIM + lane] = accA + bv;
        if (vB < N_NODES) out[(size_t)vB * DIM + lane] = accB + bv;
    }
}

// ===========================================================================
extern "C" void kernel_launch(void* const* d_in, const int* in_sizes, int n_in,
                              void* d_out, int out_size, void* d_ws, size_t ws_size,
                              hipStream_t stream) {
    const float* feat   = (const float*)d_in[0];
    const float* edge_w = (const float*)d_in[1];
    const int*   src    = (const int*)d_in[2];
    const int*   dst    = (const int*)d_in[3];
    const float* weight = (const float*)d_in[4];
    const float* bias   = (const float*)d_in[5];
    float* out = (float*)d_out;

    size_t gb_sz   = (size_t)N_NODES * DIM * 2;              // 12.8 MB (bf16)
    gb_sz = (gb_sz + 255) & ~(size_t)255;
    size_t srt_sz  = (size_t)N_NODES * CAP * 8;              // 25.6 MB
    size_t cur_sz  = (size_t)N_NODES * 4;                    // 0.4 MB
    size_t meta_sz = 64;
    size_t ovf_sz  = (size_t)OVF_CAP * 16;                   // 1 MB
    size_t neededA = gb_sz + srt_sz + cur_sz + meta_sz + ovf_sz;  // ~39.8 MB

    size_t g_sz    = (size_t)N_NODES * DIM * 4;
    size_t srtB_sz = (size_t)SRT_CAP * 8;

    if (ws_size >= neededA) {
        char* base = (char*)d_ws;
        unsigned short* g = (unsigned short*)base;
        uint2*    srt     = (uint2*)(base + gb_sz);
        unsigned* cursor  = (unsigned*)(base + gb_sz + srt_sz);
        unsigned* ovf_cnt = (unsigned*)(base + gb_sz + srt_sz + cur_sz);
        uint4*    ovf     = (uint4*)(base + gb_sz + srt_sz + cur_sz + meta_sz);

        init_kernel<<<(N_NODES + 255) / 256, 256, 0, stream>>>(cursor, ovf_cnt);
        scatter_fixed_kernel<<<2048, 256, 0, stream>>>(src, dst, edge_w,
                                                       cursor, srt, ovf_cnt, ovf);
        gemm_g_bf16_kernel<<<1563, 256, 0, stream>>>(feat, weight, g);
        pull_fixed_kernel<<<2048, 256, 0, stream>>>(g, srt, cursor, bias, out);
        cleanup_ovf_kernel<<<64, 256, 0, stream>>>(g, ovf, ovf_cnt, out);
    } else {
        // R7 exact padded-CSR path (proven, fp32 g)
        float*    g        = (float*)d_ws;
        uint2*    srt      = (uint2*)((char*)d_ws + g_sz);
        unsigned* cnt      = (unsigned*)((char*)d_ws + g_sz + srtB_sz);
        unsigned* off      = cnt + N_NODES;
        unsigned* cursor   = off + N_NODES + 1;
        unsigned* partials = cursor + N_NODES;

        zero_u32<<<(N_NODES + 255) / 256, 256, 0, stream>>>(cnt, N_NODES);
        zero_u32<<<2048, 256, 0, stream>>>((unsigned*)srt, SRT_CAP * 2);
        hist_kernel<<<2048, 256, 0, stream>>>(dst, cnt);
        scan1_kernel<<<NSCAN, 1024, 0, stream>>>(cnt, off, partials);
        scan2_kernel<<<1, 64, 0, stream>>>(partials);
        scan3_kernel<<<(N_NODES + 256) / 256, 256, 0, stream>>>(off, partials, cursor);
        scatter_sort_kernel<<<2048, 256, 0, stream>>>(src, dst, edge_w, cursor, srt);
        gemm_g_kernel<<<1563, 256, 0, stream>>>(feat, weight, g);
        pull_scalar_kernel<<<2048, 256, 0, stream>>>(g, srt, off, bias, out);
    }
}

// Round 18
// 184.406 us; speedup vs baseline: 1.5466x; 1.2242x over previous
//
#include <hip/hip_runtime.h>

#define N_NODES 100000
#define N_EDGES 1600000
#define DIM 64

#define NSLICE 8
#define SLICE_NODES ((N_NODES + NSLICE - 1) / NSLICE)     // 12500 nodes/slice

#define CAP 32                     // 256B-aligned node rows (proven R8/R16)
#define OVF_CAP 65536

// ---- legacy exact-CSR path constants (fallback) ----
#define SCAN_BLK 2048
#define NSCAN ((N_NODES + 1 + SCAN_BLK - 1) / SCAN_BLK)
#define SRT_CAP (N_EDGES + 4 * N_NODES)

typedef float fv2 __attribute__((ext_vector_type(2)));   // native vec for nt-store

__device__ __forceinline__ unsigned short f2bf(float f) {
    unsigned b = __float_as_uint(f);
    return (unsigned short)((b + 0x7FFFu + ((b >> 16) & 1u)) >> 16);  // RNE
}
__device__ __forceinline__ float bf2f(unsigned short u) {
    return __uint_as_float(((unsigned)u) << 16);
}

// ===========================================================================
// Path A: R16 scatter/gemm + half-wave pull (2x fewer VMEM instructions)
// ===========================================================================

__global__ void init_kernel(unsigned* __restrict__ cursor,
                            unsigned* __restrict__ ovf_cnt) {
    int i = blockIdx.x * blockDim.x + threadIdx.x;
    if (i < N_NODES) cursor[i] = 0u;
    if (i == 0) *ovf_cnt = 0u;
}

// EXACT R8/R16 scatter config (unchanged): 1 edge/thread/iter, nontemporal
// streaming loads, grid 2048, CAP=32 (whole-line node rows).
__global__ void scatter_fixed_kernel(const int* __restrict__ src,
                                     const int* __restrict__ dst,
                                     const float* __restrict__ w,
                                     unsigned* __restrict__ cursor,
                                     uint2* __restrict__ srt,
                                     unsigned* __restrict__ ovf_cnt,
                                     uint4* __restrict__ ovf) {
    int slice = blockIdx.x & (NSLICE - 1);
    int chunk = blockIdx.x >> 3;
    int nchunks = gridDim.x >> 3;
    int lo = slice * SLICE_NODES;
    int hi = lo + SLICE_NODES; if (hi > N_NODES) hi = N_NODES;
    int per = (N_EDGES + nchunks - 1) / nchunks;
    int e0 = chunk * per;
    int e1 = e0 + per; if (e1 > N_EDGES) e1 = N_EDGES;
    for (int e = e0 + threadIdx.x; e < e1; e += blockDim.x) {
        int d = __builtin_nontemporal_load(&dst[e]);
        if (d >= lo && d < hi) {
            int s = __builtin_nontemporal_load(&src[e]);
            float ww = __builtin_nontemporal_load(&w[e]);
            unsigned pos = atomicAdd(&cursor[d], 1u);
            if (pos < CAP) {
                srt[(size_t)d * CAP + pos] =
                    make_uint2((unsigned)s, __float_as_uint(ww));
            } else {
                unsigned op = atomicAdd(ovf_cnt, 1u);
                if (op < OVF_CAP)
                    ovf[op] = make_uint4((unsigned)d, (unsigned)s,
                                         __float_as_uint(ww), 0u);
            }
        }
    }
}

// g = feat @ W, stored BF16 (unchanged from R16).
__global__ __launch_bounds__(256) void gemm_g_bf16_kernel(
        const float* __restrict__ feat, const float* __restrict__ W,
        unsigned short* __restrict__ g) {
    __shared__ float4 ft[64 * 16];   // 16 KB
    int tid = threadIdx.x, lane = tid & 63, wv = tid >> 6;

    float Wreg[DIM];
#pragma unroll
    for (int k = 0; k < DIM; ++k) Wreg[k] = W[k * DIM + lane];

    const float4* feat4 = (const float4*)feat;
    for (int tile = blockIdx.x; tile * 64 < N_NODES; tile += gridDim.x) {
        int base = tile * 64;
        int nrows = N_NODES - base; if (nrows > 64) nrows = 64;
        __syncthreads();
        for (int i = tid; i < 64 * 16; i += 256) {
            int r = i >> 4;
            ft[i] = (r < nrows) ? feat4[(size_t)(base + r) * 16 + (i & 15)]
                                : float4{0.f, 0.f, 0.f, 0.f};
        }
        __syncthreads();
        for (int r = wv; r < nrows; r += 4) {
            float acc = 0.f;
#pragma unroll
            for (int k4 = 0; k4 < 16; ++k4) {
                float4 f = ft[r * 16 + k4];   // uniform -> LDS broadcast
                acc = fmaf(f.x, Wreg[4 * k4 + 0], acc);
                acc = fmaf(f.y, Wreg[4 * k4 + 1], acc);
                acc = fmaf(f.z, Wreg[4 * k4 + 2], acc);
                acc = fmaf(f.w, Wreg[4 * k4 + 3], acc);
            }
            g[(size_t)(base + r) * DIM + lane] = f2bf(acc);
        }
    }
}

// Half-wave pull: lanes 0-31 own node v0, lanes 32-63 own node v0+1; each
// lane covers dims {2*ln2, 2*ln2+1} via ONE packed-bf16x2 uint gather.
// Per edge-step k: 1 srt load + 1 gather serve BOTH nodes -> 2x fewer VMEM
// instructions than R16's pull at identical traffic.
__global__ __launch_bounds__(256) void pull_half_kernel(
        const unsigned short* __restrict__ g, const uint2* __restrict__ srt,
        const unsigned* __restrict__ cursor, const float* __restrict__ bias,
        float* __restrict__ out) {
    int tid = threadIdx.x;
    int lane = tid & 63;
    int half = lane >> 5;          // 0 -> node v0, 1 -> node v0+1
    int ln2 = lane & 31;           // covers dims 2*ln2, 2*ln2+1
    float bv0 = bias[2 * ln2 + 0];
    float bv1 = bias[2 * ln2 + 1];
    int gw = (int)((blockIdx.x * blockDim.x + tid) >> 6);
    int nw = (int)((gridDim.x * blockDim.x) >> 6);

    const unsigned* g32 = (const unsigned*)g;   // packed bf16x2 view

    for (int v0 = 2 * gw; v0 < N_NODES; v0 += 2 * nw) {
        uint2 cpair = *(const uint2*)&cursor[v0];          // v0 even, aligned
        int cA = (int)__builtin_amdgcn_readfirstlane((int)cpair.x);
        int cB = (int)__builtin_amdgcn_readfirstlane((int)cpair.y);
        cA = cA < CAP ? cA : CAP;
        cB = cB < CAP ? cB : CAP;
        int myc = half ? cB : cA;
        const uint2* p = srt + (size_t)(v0 + half) * CAP;

        float a0 = 0.f, a1 = 0.f;
        int kmax = cA > cB ? cA : cB;
        for (int k = 0; k < kmax; k += 4) {
#pragma unroll
            for (int j = 0; j < 4; ++j) {
                uint2 e = p[k + j];                        // in-bounds (CAP slots)
                unsigned s = (k + j < myc) ? e.x : 0u;     // scalar selects
                float   ww = (k + j < myc) ? __uint_as_float(e.y) : 0.f;
                unsigned pk = g32[(size_t)s * (DIM / 2) + ln2];
                float glo = __uint_as_float(pk << 16);           // dim 2*ln2
                float ghi = __uint_as_float(pk & 0xFFFF0000u);   // dim 2*ln2+1
                a0 = fmaf(glo, ww, a0);
                a1 = fmaf(ghi, ww, a1);
            }
        }
        fv2 r;
        r.x = a0 + bv0;
        r.y = a1 + bv1;
        __builtin_nontemporal_store(
            r, (fv2*)&out[(size_t)(v0 + half) * DIM + 2 * ln2]);
    }
}

// Apply rare overflow edges (pos >= CAP) after pull wrote out.
__global__ void cleanup_ovf_kernel(const unsigned short* __restrict__ g,
                                   const uint4* __restrict__ ovf,
                                   const unsigned* __restrict__ ovf_cnt,
                                   float* __restrict__ out) {
    int lane = threadIdx.x & 63;
    int wv = (int)((blockIdx.x * blockDim.x + threadIdx.x) >> 6);
    int nwv = (int)((gridDim.x * blockDim.x) >> 6);
    unsigned nraw = *ovf_cnt;
    int n = (int)(nraw < (unsigned)OVF_CAP ? nraw : (unsigned)OVF_CAP);
    for (int i = wv; i < n; i += nwv) {
        uint4 t = ovf[i];
        atomicAdd(&out[(size_t)t.x * DIM + lane],
                  bf2f(g[(size_t)t.y * DIM + lane]) * __uint_as_float(t.z));
    }
}

// ===========================================================================
// Path B (fallback): R7 exact padded-CSR pipeline (fp32 g)
// ===========================================================================

__global__ void zero_u32(unsigned* __restrict__ p, int n) {
    int stride = gridDim.x * blockDim.x;
    for (int i = blockIdx.x * blockDim.x + threadIdx.x; i < n; i += stride)
        p[i] = 0u;
}

__global__ __launch_bounds__(256) void gemm_g_kernel(const float* __restrict__ feat,
                                                     const float* __restrict__ W,
                                                     float* __restrict__ g) {
    __shared__ float4 ft[64 * 16];
    int tid = threadIdx.x, lane = tid & 63, wv = tid >> 6;
    float Wreg[DIM];
#pragma unroll
    for (int k = 0; k < DIM; ++k) Wreg[k] = W[k * DIM + lane];
    const float4* feat4 = (const float4*)feat;
    for (int tile = blockIdx.x; tile * 64 < N_NODES; tile += gridDim.x) {
        int base = tile * 64;
        int nrows = N_NODES - base; if (nrows > 64) nrows = 64;
        __syncthreads();
        for (int i = tid; i < 64 * 16; i += 256) {
            int r = i >> 4;
            ft[i] = (r < nrows) ? feat4[(size_t)(base + r) * 16 + (i & 15)]
                                : float4{0.f, 0.f, 0.f, 0.f};
        }
        __syncthreads();
        for (int r = wv; r < nrows; r += 4) {
            float acc = 0.f;
#pragma unroll
            for (int k4 = 0; k4 < 16; ++k4) {
                float4 f = ft[r * 16 + k4];
                acc = fmaf(f.x, Wreg[4 * k4 + 0], acc);
                acc = fmaf(f.y, Wreg[4 * k4 + 1], acc);
                acc = fmaf(f.z, Wreg[4 * k4 + 2], acc);
                acc = fmaf(f.w, Wreg[4 * k4 + 3], acc);
            }
            g[(size_t)(base + r) * DIM + lane] = acc;
        }
    }
}

__global__ void hist_kernel(const int* __restrict__ dst, unsigned* __restrict__ cnt) {
    int slice = blockIdx.x & (NSLICE - 1);
    int chunk = blockIdx.x >> 3;
    int nchunks = gridDim.x >> 3;
    int lo = slice * SLICE_NODES;
    int hi = lo + SLICE_NODES; if (hi > N_NODES) hi = N_NODES;
    int per = (N_EDGES + nchunks - 1) / nchunks;
    int e0 = chunk * per;
    int e1 = e0 + per; if (e1 > N_EDGES) e1 = N_EDGES;
    for (int e = e0 + threadIdx.x; e < e1; e += blockDim.x) {
        int d = dst[e];
        if (d >= lo && d < hi) atomicAdd(&cnt[d], 1u);
    }
}

__global__ void scan1_kernel(const unsigned* __restrict__ cnt,
                             unsigned* __restrict__ off,
                             unsigned* __restrict__ partials) {
    __shared__ unsigned s[SCAN_BLK];
    int t = threadIdx.x;
    int base = blockIdx.x * SCAN_BLK;
    int i0 = base + t, i1 = base + t + 1024;
    unsigned c0 = (i0 < N_NODES) ? ((cnt[i0] + 3u) & ~3u) : 0u;
    unsigned c1 = (i1 < N_NODES) ? ((cnt[i1] + 3u) & ~3u) : 0u;
    s[t] = c0;
    s[t + 1024] = c1;
    __syncthreads();
    for (int o = 1; o < SCAN_BLK; o <<= 1) {
        unsigned a0 = s[t];
        unsigned a1 = s[t + 1024];
        unsigned b0 = (t >= o) ? s[t - o] : 0u;
        unsigned b1 = (t + 1024 >= o) ? s[t + 1024 - o] : 0u;
        __syncthreads();
        s[t] = a0 + b0;
        s[t + 1024] = a1 + b1;
        __syncthreads();
    }
    for (int i = t; i < SCAN_BLK; i += 1024) {
        int gg = base + i;
        if (gg <= N_NODES) off[gg] = (i == 0) ? 0u : s[i - 1];
    }
    if (t == 0) partials[blockIdx.x] = s[SCAN_BLK - 1];
}

__global__ void scan2_kernel(unsigned* __restrict__ partials) {
    int t = threadIdx.x;
    unsigned v = (t < NSCAN) ? partials[t] : 0u;
    unsigned orig = v;
    for (int o = 1; o < 64; o <<= 1) {
        unsigned n = __shfl_up(v, o, 64);
        if (t >= o) v += n;
    }
    if (t < NSCAN) partials[t] = v - orig;
}

__global__ void scan3_kernel(unsigned* __restrict__ off,
                             const unsigned* __restrict__ partials,
                             unsigned* __restrict__ cursor) {
    int i = blockIdx.x * blockDim.x + threadIdx.x;
    if (i <= N_NODES) {
        unsigned v = off[i] + partials[i / SCAN_BLK];
        off[i] = v;
        if (i < N_NODES) cursor[i] = v;
    }
}

__global__ void scatter_sort_kernel(const int* __restrict__ src,
                                    const int* __restrict__ dst,
                                    const float* __restrict__ w,
                                    unsigned* __restrict__ cursor,
                                    uint2* __restrict__ srt) {
    int slice = blockIdx.x & (NSLICE - 1);
    int chunk = blockIdx.x >> 3;
    int nchunks = gridDim.x >> 3;
    int lo = slice * SLICE_NODES;
    int hi = lo + SLICE_NODES; if (hi > N_NODES) hi = N_NODES;
    int per = (N_EDGES + nchunks - 1) / nchunks;
    int e0 = chunk * per;
    int e1 = e0 + per; if (e1 > N_EDGES) e1 = N_EDGES;
    for (int e = e0 + threadIdx.x; e < e1; e += blockDim.x) {
        int d = dst[e];
        if (d >= lo && d < hi) {
            unsigned pos = atomicAdd(&cursor[d], 1u);
            srt[pos] = make_uint2((unsigned)src[e], __float_as_uint(w[e]));
        }
    }
}

__global__ __launch_bounds__(256) void pull_scalar_kernel(
        const float* __restrict__ g, const uint2* __restrict__ srt,
        const unsigned* __restrict__ off, const float* __restrict__ bias,
        float* __restrict__ out) {
    int tid = threadIdx.x, lane = tid & 63;
    float bv = bias[lane];
    int gw = (int)((blockIdx.x * blockDim.x + tid) >> 6);
    int nw = (int)((gridDim.x * blockDim.x) >> 6);

    for (int v = gw; v < N_NODES; v += 2 * nw) {
        int vB = v + nw;
        int bA = (int)__builtin_amdgcn_readfirstlane((int)off[v]);
        int cA = (int)__builtin_amdgcn_readfirstlane((int)off[v + 1]) - bA;
        int bB = 0, cB = 0;
        if (vB < N_NODES) {
            bB = (int)__builtin_amdgcn_readfirstlane((int)off[vB]);
            cB = (int)__builtin_amdgcn_readfirstlane((int)off[vB + 1]) - bB;
        }
        float accA = 0.f, accB = 0.f;
        int kmax = cA > cB ? cA : cB;
        for (int k = 0; k < kmax; k += 4) {
            if (k < cA) {
                uint2 e0 = srt[bA + k + 0];
                uint2 e1 = srt[bA + k + 1];
                uint2 e2 = srt[bA + k + 2];
                uint2 e3 = srt[bA + k + 3];
                accA = fmaf(g[e0.x * DIM + lane], __uint_as_float(e0.y), accA);
                accA = fmaf(g[e1.x * DIM + lane], __uint_as_float(e1.y), accA);
                accA = fmaf(g[e2.x * DIM + lane], __uint_as_float(e2.y), accA);
                accA = fmaf(g[e3.x * DIM + lane], __uint_as_float(e3.y), accA);
            }
            if (k < cB) {
                uint2 e0 = srt[bB + k + 0];
                uint2 e1 = srt[bB + k + 1];
                uint2 e2 = srt[bB + k + 2];
                uint2 e3 = srt[bB + k + 3];
                accB = fmaf(g[e0.x * DIM + lane], __uint_as_float(e0.y), accB);
                accB = fmaf(g[e1.x * DIM + lane], __uint_as_float(e1.y), accB);
                accB = fmaf(g[e2.x * DIM + lane], __uint_as_float(e2.y), accB);
                accB = fmaf(g[e3.x * DIM + lane], __uint_as_float(e3.y), accB);
            }
        }
        out[(size_t)v * DIM + lane] = accA + bv;
        if (vB < N_NODES) out[(size_t)vB * DIM + lane] = accB + bv;
    }
}

// ===========================================================================
extern "C" void kernel_launch(void* const* d_in, const int* in_sizes, int n_in,
                              void* d_out, int out_size, void* d_ws, size_t ws_size,
                              hipStream_t stream) {
    const float* feat   = (const float*)d_in[0];
    const float* edge_w = (const float*)d_in[1];
    const int*   src    = (const int*)d_in[2];
    const int*   dst    = (const int*)d_in[3];
    const float* weight = (const float*)d_in[4];
    const float* bias   = (const float*)d_in[5];
    float* out = (float*)d_out;

    size_t gb_sz   = (size_t)N_NODES * DIM * 2;              // 12.8 MB (bf16)
    gb_sz = (gb_sz + 255) & ~(size_t)255;
    size_t srt_sz  = (size_t)N_NODES * CAP * 8;              // 25.6 MB
    size_t cur_sz  = (size_t)N_NODES * 4;                    // 0.4 MB
    size_t meta_sz = 64;
    size_t ovf_sz  = (size_t)OVF_CAP * 16;                   // 1 MB
    size_t neededA = gb_sz + srt_sz + cur_sz + meta_sz + ovf_sz;  // ~39.8 MB

    size_t g_sz    = (size_t)N_NODES * DIM * 4;
    size_t srtB_sz = (size_t)SRT_CAP * 8;

    if (ws_size >= neededA) {
        char* base = (char*)d_ws;
        unsigned short* g = (unsigned short*)base;
        uint2*    srt     = (uint2*)(base + gb_sz);
        unsigned* cursor  = (unsigned*)(base + gb_sz + srt_sz);
        unsigned* ovf_cnt = (unsigned*)(base + gb_sz + srt_sz + cur_sz);
        uint4*    ovf     = (uint4*)(base + gb_sz + srt_sz + cur_sz + meta_sz);

        init_kernel<<<(N_NODES + 255) / 256, 256, 0, stream>>>(cursor, ovf_cnt);
        scatter_fixed_kernel<<<2048, 256, 0, stream>>>(src, dst, edge_w,
                                                       cursor, srt, ovf_cnt, ovf);
        gemm_g_bf16_kernel<<<1563, 256, 0, stream>>>(feat, weight, g);
        pull_half_kernel<<<2048, 256, 0, stream>>>(g, srt, cursor, bias, out);
        cleanup_ovf_kernel<<<64, 256, 0, stream>>>(g, ovf, ovf_cnt, out);
    } else {
        // R7 exact padded-CSR path (proven, fp32 g)
        float*    g        = (float*)d_ws;
        uint2*    srt      = (uint2*)((char*)d_ws + g_sz);
        unsigned* cnt      = (unsigned*)((char*)d_ws + g_sz + srtB_sz);
        unsigned* off      = cnt + N_NODES;
        unsigned* cursor   = off + N_NODES + 1;
        unsigned* partials = cursor + N_NODES;

        zero_u32<<<(N_NODES + 255) / 256, 256, 0, stream>>>(cnt, N_NODES);
        zero_u32<<<2048, 256, 0, stream>>>((unsigned*)srt, SRT_CAP * 2);
        hist_kernel<<<2048, 256, 0, stream>>>(dst, cnt);
        scan1_kernel<<<NSCAN, 1024, 0, stream>>>(cnt, off, partials);
        scan2_kernel<<<1, 64, 0, stream>>>(partials);
        scan3_kernel<<<(N_NODES + 256) / 256, 256, 0, stream>>>(off, partials, cursor);
        scatter_sort_kernel<<<2048, 256, 0, stream>>>(src, dst, edge_w, cursor, srt);
        gemm_g_kernel<<<1563, 256, 0, stream>>>(feat, weight, g);
        pull_scalar_kernel<<<2048, 256, 0, stream>>>(g, srt, off, bias, out);
    }
}

// Round 19
// 169.260 us; speedup vs baseline: 1.6850x; 1.0895x over previous
//
#include <hip/hip_runtime.h>

#define N_NODES 100000
#define N_EDGES 1600000
#define DIM 64

#define NSLICE 8
#define SLICE_NODES ((N_NODES + NSLICE - 1) / NSLICE)     // 12500 nodes/slice

#define CAP 32                     // 256B-aligned node rows (proven R8/R16)
#define OVF_CAP 65536

// ---- legacy exact-CSR path constants (fallback) ----
#define SCAN_BLK 2048
#define NSCAN ((N_NODES + 1 + SCAN_BLK - 1) / SCAN_BLK)
#define SRT_CAP (N_EDGES + 4 * N_NODES)

typedef float fv4 __attribute__((ext_vector_type(4)));   // native vec for nt-store

__device__ __forceinline__ unsigned short f2bf(float f) {
    unsigned b = __float_as_uint(f);
    return (unsigned short)((b + 0x7FFFu + ((b >> 16) & 1u)) >> 16);  // RNE
}
__device__ __forceinline__ float bf2f(unsigned short u) {
    return __uint_as_float(((unsigned)u) << 16);
}

// ===========================================================================
// Path A: R16 scatter/gemm + quarter-wave pull (4x fewer VMEM instructions
// than the R16 full-wave pull)
// ===========================================================================

__global__ void init_kernel(unsigned* __restrict__ cursor,
                            unsigned* __restrict__ ovf_cnt) {
    int i = blockIdx.x * blockDim.x + threadIdx.x;
    if (i < N_NODES) cursor[i] = 0u;
    if (i == 0) *ovf_cnt = 0u;
}

// EXACT R8/R16 scatter config (unchanged): 1 edge/thread/iter, nontemporal
// streaming loads, grid 2048, CAP=32 (whole-line node rows).
__global__ void scatter_fixed_kernel(const int* __restrict__ src,
                                     const int* __restrict__ dst,
                                     const float* __restrict__ w,
                                     unsigned* __restrict__ cursor,
                                     uint2* __restrict__ srt,
                                     unsigned* __restrict__ ovf_cnt,
                                     uint4* __restrict__ ovf) {
    int slice = blockIdx.x & (NSLICE - 1);
    int chunk = blockIdx.x >> 3;
    int nchunks = gridDim.x >> 3;
    int lo = slice * SLICE_NODES;
    int hi = lo + SLICE_NODES; if (hi > N_NODES) hi = N_NODES;
    int per = (N_EDGES + nchunks - 1) / nchunks;
    int e0 = chunk * per;
    int e1 = e0 + per; if (e1 > N_EDGES) e1 = N_EDGES;
    for (int e = e0 + threadIdx.x; e < e1; e += blockDim.x) {
        int d = __builtin_nontemporal_load(&dst[e]);
        if (d >= lo && d < hi) {
            int s = __builtin_nontemporal_load(&src[e]);
            float ww = __builtin_nontemporal_load(&w[e]);
            unsigned pos = atomicAdd(&cursor[d], 1u);
            if (pos < CAP) {
                srt[(size_t)d * CAP + pos] =
                    make_uint2((unsigned)s, __float_as_uint(ww));
            } else {
                unsigned op = atomicAdd(ovf_cnt, 1u);
                if (op < OVF_CAP)
                    ovf[op] = make_uint4((unsigned)d, (unsigned)s,
                                         __float_as_uint(ww), 0u);
            }
        }
    }
}

// g = feat @ W, stored BF16 (unchanged from R16).
__global__ __launch_bounds__(256) void gemm_g_bf16_kernel(
        const float* __restrict__ feat, const float* __restrict__ W,
        unsigned short* __restrict__ g) {
    __shared__ float4 ft[64 * 16];   // 16 KB
    int tid = threadIdx.x, lane = tid & 63, wv = tid >> 6;

    float Wreg[DIM];
#pragma unroll
    for (int k = 0; k < DIM; ++k) Wreg[k] = W[k * DIM + lane];

    const float4* feat4 = (const float4*)feat;
    for (int tile = blockIdx.x; tile * 64 < N_NODES; tile += gridDim.x) {
        int base = tile * 64;
        int nrows = N_NODES - base; if (nrows > 64) nrows = 64;
        __syncthreads();
        for (int i = tid; i < 64 * 16; i += 256) {
            int r = i >> 4;
            ft[i] = (r < nrows) ? feat4[(size_t)(base + r) * 16 + (i & 15)]
                                : float4{0.f, 0.f, 0.f, 0.f};
        }
        __syncthreads();
        for (int r = wv; r < nrows; r += 4) {
            float acc = 0.f;
#pragma unroll
            for (int k4 = 0; k4 < 16; ++k4) {
                float4 f = ft[r * 16 + k4];   // uniform -> LDS broadcast
                acc = fmaf(f.x, Wreg[4 * k4 + 0], acc);
                acc = fmaf(f.y, Wreg[4 * k4 + 1], acc);
                acc = fmaf(f.z, Wreg[4 * k4 + 2], acc);
                acc = fmaf(f.w, Wreg[4 * k4 + 3], acc);
            }
            g[(size_t)(base + r) * DIM + lane] = f2bf(acc);
        }
    }
}

// Quarter-wave pull: 4 adjacent nodes per wave (16 lanes each). Lane group
// q = lane>>4 owns node v0+q; ln4 = lane&15 covers dims 4*ln4..4*ln4+3 via
// ONE packed-bf16x4 uint2 gather (16 lanes x 8B = full 128B row). Per
// edge-step: 1 srt load + 1 gather serve 4 nodes. Grid 1563 -> 6252 waves
// x 4 nodes = 25008 nodes/iter -> exactly 4 balanced outer iterations.
__global__ __launch_bounds__(256) void pull_quarter_kernel(
        const unsigned short* __restrict__ g, const uint2* __restrict__ srt,
        const unsigned* __restrict__ cursor, const float* __restrict__ bias,
        float* __restrict__ out) {
    int tid = threadIdx.x;
    int lane = tid & 63;
    int q = lane >> 4;             // node v0+q
    int ln4 = lane & 15;           // dims 4*ln4 .. 4*ln4+3
    float bv0 = bias[4 * ln4 + 0];
    float bv1 = bias[4 * ln4 + 1];
    float bv2 = bias[4 * ln4 + 2];
    float bv3 = bias[4 * ln4 + 3];
    int gw = (int)((blockIdx.x * blockDim.x + tid) >> 6);
    int nw = (int)((gridDim.x * blockDim.x) >> 6);

    const uint2* g64 = (const uint2*)g;   // packed bf16x4 view (8B per 4 dims)

    for (int v0 = 4 * gw; v0 < N_NODES; v0 += 4 * nw) {
        uint4 cq = *(const uint4*)&cursor[v0];             // v0 mult of 4, aligned
        int c0 = (int)__builtin_amdgcn_readfirstlane((int)cq.x);
        int c1 = (int)__builtin_amdgcn_readfirstlane((int)cq.y);
        int c2 = (int)__builtin_amdgcn_readfirstlane((int)cq.z);
        int c3 = (int)__builtin_amdgcn_readfirstlane((int)cq.w);
        c0 = c0 < CAP ? c0 : CAP;
        c1 = c1 < CAP ? c1 : CAP;
        c2 = c2 < CAP ? c2 : CAP;
        c3 = c3 < CAP ? c3 : CAP;
        int myc = (q == 0) ? c0 : (q == 1) ? c1 : (q == 2) ? c2 : c3;
        const uint2* p = srt + (size_t)(v0 + q) * CAP;

        float a0 = 0.f, a1 = 0.f, a2 = 0.f, a3 = 0.f;
        int m01 = c0 > c1 ? c0 : c1;
        int m23 = c2 > c3 ? c2 : c3;
        int kmax = m01 > m23 ? m01 : m23;
        for (int k = 0; k < kmax; k += 4) {
#pragma unroll
            for (int j = 0; j < 4; ++j) {
                uint2 e = p[k + j];                        // in-bounds (CAP slots)
                unsigned s = (k + j < myc) ? e.x : 0u;     // scalar selects
                float   ww = (k + j < myc) ? __uint_as_float(e.y) : 0.f;
                uint2 pk = g64[(size_t)s * (DIM / 4) + ln4];
                a0 = fmaf(__uint_as_float(pk.x << 16), ww, a0);
                a1 = fmaf(__uint_as_float(pk.x & 0xFFFF0000u), ww, a1);
                a2 = fmaf(__uint_as_float(pk.y << 16), ww, a2);
                a3 = fmaf(__uint_as_float(pk.y & 0xFFFF0000u), ww, a3);
            }
        }
        fv4 r;
        r.x = a0 + bv0;
        r.y = a1 + bv1;
        r.z = a2 + bv2;
        r.w = a3 + bv3;
        __builtin_nontemporal_store(
            r, (fv4*)&out[(size_t)(v0 + q) * DIM + 4 * ln4]);
    }
}

// Apply rare overflow edges (pos >= CAP) after pull wrote out.
__global__ void cleanup_ovf_kernel(const unsigned short* __restrict__ g,
                                   const uint4* __restrict__ ovf,
                                   const unsigned* __restrict__ ovf_cnt,
                                   float* __restrict__ out) {
    int lane = threadIdx.x & 63;
    int wv = (int)((blockIdx.x * blockDim.x + threadIdx.x) >> 6);
    int nwv = (int)((gridDim.x * blockDim.x) >> 6);
    unsigned nraw = *ovf_cnt;
    int n = (int)(nraw < (unsigned)OVF_CAP ? nraw : (unsigned)OVF_CAP);
    for (int i = wv; i < n; i += nwv) {
        uint4 t = ovf[i];
        atomicAdd(&out[(size_t)t.x * DIM + lane],
                  bf2f(g[(size_t)t.y * DIM + lane]) * __uint_as_float(t.z));
    }
}

// ===========================================================================
// Path B (fallback): R7 exact padded-CSR pipeline (fp32 g)
// ===========================================================================

__global__ void zero_u32(unsigned* __restrict__ p, int n) {
    int stride = gridDim.x * blockDim.x;
    for (int i = blockIdx.x * blockDim.x + threadIdx.x; i < n; i += stride)
        p[i] = 0u;
}

__global__ __launch_bounds__(256) void gemm_g_kernel(const float* __restrict__ feat,
                                                     const float* __restrict__ W,
                                                     float* __restrict__ g) {
    __shared__ float4 ft[64 * 16];
    int tid = threadIdx.x, lane = tid & 63, wv = tid >> 6;
    float Wreg[DIM];
#pragma unroll
    for (int k = 0; k < DIM; ++k) Wreg[k] = W[k * DIM + lane];
    const float4* feat4 = (const float4*)feat;
    for (int tile = blockIdx.x; tile * 64 < N_NODES; tile += gridDim.x) {
        int base = tile * 64;
        int nrows = N_NODES - base; if (nrows > 64) nrows = 64;
        __syncthreads();
        for (int i = tid; i < 64 * 16; i += 256) {
            int r = i >> 4;
            ft[i] = (r < nrows) ? feat4[(size_t)(base + r) * 16 + (i & 15)]
                                : float4{0.f, 0.f, 0.f, 0.f};
        }
        __syncthreads();
        for (int r = wv; r < nrows; r += 4) {
            float acc = 0.f;
#pragma unroll
            for (int k4 = 0; k4 < 16; ++k4) {
                float4 f = ft[r * 16 + k4];
                acc = fmaf(f.x, Wreg[4 * k4 + 0], acc);
                acc = fmaf(f.y, Wreg[4 * k4 + 1], acc);
                acc = fmaf(f.z, Wreg[4 * k4 + 2], acc);
                acc = fmaf(f.w, Wreg[4 * k4 + 3], acc);
            }
            g[(size_t)(base + r) * DIM + lane] = acc;
        }
    }
}

__global__ void hist_kernel(const int* __restrict__ dst, unsigned* __restrict__ cnt) {
    int slice = blockIdx.x & (NSLICE - 1);
    int chunk = blockIdx.x >> 3;
    int nchunks = gridDim.x >> 3;
    int lo = slice * SLICE_NODES;
    int hi = lo + SLICE_NODES; if (hi > N_NODES) hi = N_NODES;
    int per = (N_EDGES + nchunks - 1) / nchunks;
    int e0 = chunk * per;
    int e1 = e0 + per; if (e1 > N_EDGES) e1 = N_EDGES;
    for (int e = e0 + threadIdx.x; e < e1; e += blockDim.x) {
        int d = dst[e];
        if (d >= lo && d < hi) atomicAdd(&cnt[d], 1u);
    }
}

__global__ void scan1_kernel(const unsigned* __restrict__ cnt,
                             unsigned* __restrict__ off,
                             unsigned* __restrict__ partials) {
    __shared__ unsigned s[SCAN_BLK];
    int t = threadIdx.x;
    int base = blockIdx.x * SCAN_BLK;
    int i0 = base + t, i1 = base + t + 1024;
    unsigned c0 = (i0 < N_NODES) ? ((cnt[i0] + 3u) & ~3u) : 0u;
    unsigned c1 = (i1 < N_NODES) ? ((cnt[i1] + 3u) & ~3u) : 0u;
    s[t] = c0;
    s[t + 1024] = c1;
    __syncthreads();
    for (int o = 1; o < SCAN_BLK; o <<= 1) {
        unsigned a0 = s[t];
        unsigned a1 = s[t + 1024];
        unsigned b0 = (t >= o) ? s[t - o] : 0u;
        unsigned b1 = (t + 1024 >= o) ? s[t + 1024 - o] : 0u;
        __syncthreads();
        s[t] = a0 + b0;
        s[t + 1024] = a1 + b1;
        __syncthreads();
    }
    for (int i = t; i < SCAN_BLK; i += 1024) {
        int gg = base + i;
        if (gg <= N_NODES) off[gg] = (i == 0) ? 0u : s[i - 1];
    }
    if (t == 0) partials[blockIdx.x] = s[SCAN_BLK - 1];
}

__global__ void scan2_kernel(unsigned* __restrict__ partials) {
    int t = threadIdx.x;
    unsigned v = (t < NSCAN) ? partials[t] : 0u;
    unsigned orig = v;
    for (int o = 1; o < 64; o <<= 1) {
        unsigned n = __shfl_up(v, o, 64);
        if (t >= o) v += n;
    }
    if (t < NSCAN) partials[t] = v - orig;
}

__global__ void scan3_kernel(unsigned* __restrict__ off,
                             const unsigned* __restrict__ partials,
                             unsigned* __restrict__ cursor) {
    int i = blockIdx.x * blockDim.x + threadIdx.x;
    if (i <= N_NODES) {
        unsigned v = off[i] + partials[i / SCAN_BLK];
        off[i] = v;
        if (i < N_NODES) cursor[i] = v;
    }
}

__global__ void scatter_sort_kernel(const int* __restrict__ src,
                                    const int* __restrict__ dst,
                                    const float* __restrict__ w,
                                    unsigned* __restrict__ cursor,
                                    uint2* __restrict__ srt) {
    int slice = blockIdx.x & (NSLICE - 1);
    int chunk = blockIdx.x >> 3;
    int nchunks = gridDim.x >> 3;
    int lo = slice * SLICE_NODES;
    int hi = lo + SLICE_NODES; if (hi > N_NODES) hi = N_NODES;
    int per = (N_EDGES + nchunks - 1) / nchunks;
    int e0 = chunk * per;
    int e1 = e0 + per; if (e1 > N_EDGES) e1 = N_EDGES;
    for (int e = e0 + threadIdx.x; e < e1; e += blockDim.x) {
        int d = dst[e];
        if (d >= lo && d < hi) {
            unsigned pos = atomicAdd(&cursor[d], 1u);
            srt[pos] = make_uint2((unsigned)src[e], __float_as_uint(w[e]));
        }
    }
}

__global__ __launch_bounds__(256) void pull_scalar_kernel(
        const float* __restrict__ g, const uint2* __restrict__ srt,
        const unsigned* __restrict__ off, const float* __restrict__ bias,
        float* __restrict__ out) {
    int tid = threadIdx.x, lane = tid & 63;
    float bv = bias[lane];
    int gw = (int)((blockIdx.x * blockDim.x + tid) >> 6);
    int nw = (int)((gridDim.x * blockDim.x) >> 6);

    for (int v = gw; v < N_NODES; v += 2 * nw) {
        int vB = v + nw;
        int bA = (int)__builtin_amdgcn_readfirstlane((int)off[v]);
        int cA = (int)__builtin_amdgcn_readfirstlane((int)off[v + 1]) - bA;
        int bB = 0, cB = 0;
        if (vB < N_NODES) {
            bB = (int)__builtin_amdgcn_readfirstlane((int)off[vB]);
            cB = (int)__builtin_amdgcn_readfirstlane((int)off[vB + 1]) - bB;
        }
        float accA = 0.f, accB = 0.f;
        int kmax = cA > cB ? cA : cB;
        for (int k = 0; k < kmax; k += 4) {
            if (k < cA) {
                uint2 e0 = srt[bA + k + 0];
                uint2 e1 = srt[bA + k + 1];
                uint2 e2 = srt[bA + k + 2];
                uint2 e3 = srt[bA + k + 3];
                accA = fmaf(g[e0.x * DIM + lane], __uint_as_float(e0.y), accA);
                accA = fmaf(g[e1.x * DIM + lane], __uint_as_float(e1.y), accA);
                accA = fmaf(g[e2.x * DIM + lane], __uint_as_float(e2.y), accA);
                accA = fmaf(g[e3.x * DIM + lane], __uint_as_float(e3.y), accA);
            }
            if (k < cB) {
                uint2 e0 = srt[bB + k + 0];
                uint2 e1 = srt[bB + k + 1];
                uint2 e2 = srt[bB + k + 2];
                uint2 e3 = srt[bB + k + 3];
                accB = fmaf(g[e0.x * DIM + lane], __uint_as_float(e0.y), accB);
                accB = fmaf(g[e1.x * DIM + lane], __uint_as_float(e1.y), accB);
                accB = fmaf(g[e2.x * DIM + lane], __uint_as_float(e2.y), accB);
                accB = fmaf(g[e3.x * DIM + lane], __uint_as_float(e3.y), accB);
            }
        }
        out[(size_t)v * DIM + lane] = accA + bv;
        if (vB < N_NODES) out[(size_t)vB * DIM + lane] = accB + bv;
    }
}

// ===========================================================================
extern "C" void kernel_launch(void* const* d_in, const int* in_sizes, int n_in,
                              void* d_out, int out_size, void* d_ws, size_t ws_size,
                              hipStream_t stream) {
    const float* feat   = (const float*)d_in[0];
    const float* edge_w = (const float*)d_in[1];
    const int*   src    = (const int*)d_in[2];
    const int*   dst    = (const int*)d_in[3];
    const float* weight = (const float*)d_in[4];
    const float* bias   = (const float*)d_in[5];
    float* out = (float*)d_out;

    size_t gb_sz   = (size_t)N_NODES * DIM * 2;              // 12.8 MB (bf16)
    gb_sz = (gb_sz + 255) & ~(size_t)255;
    size_t srt_sz  = (size_t)N_NODES * CAP * 8;              // 25.6 MB
    size_t cur_sz  = (size_t)N_NODES * 4;                    // 0.4 MB
    size_t meta_sz = 64;
    size_t ovf_sz  = (size_t)OVF_CAP * 16;                   // 1 MB
    size_t neededA = gb_sz + srt_sz + cur_sz + meta_sz + ovf_sz;  // ~39.8 MB

    size_t g_sz    = (size_t)N_NODES * DIM * 4;
    size_t srtB_sz = (size_t)SRT_CAP * 8;

    if (ws_size >= neededA) {
        char* base = (char*)d_ws;
        unsigned short* g = (unsigned short*)base;
        uint2*    srt     = (uint2*)(base + gb_sz);
        unsigned* cursor  = (unsigned*)(base + gb_sz + srt_sz);
        unsigned* ovf_cnt = (unsigned*)(base + gb_sz + srt_sz + cur_sz);
        uint4*    ovf     = (uint4*)(base + gb_sz + srt_sz + cur_sz + meta_sz);

        init_kernel<<<(N_NODES + 255) / 256, 256, 0, stream>>>(cursor, ovf_cnt);
        scatter_fixed_kernel<<<2048, 256, 0, stream>>>(src, dst, edge_w,
                                                       cursor, srt, ovf_cnt, ovf);
        gemm_g_bf16_kernel<<<1563, 256, 0, stream>>>(feat, weight, g);
        pull_quarter_kernel<<<1563, 256, 0, stream>>>(g, srt, cursor, bias, out);
        cleanup_ovf_kernel<<<64, 256, 0, stream>>>(g, ovf, ovf_cnt, out);
    } else {
        // R7 exact padded-CSR path (proven, fp32 g)
        float*    g        = (float*)d_ws;
        uint2*    srt      = (uint2*)((char*)d_ws + g_sz);
        unsigned* cnt      = (unsigned*)((char*)d_ws + g_sz + srtB_sz);
        unsigned* off      = cnt + N_NODES;
        unsigned* cursor   = off + N_NODES + 1;
        unsigned* partials = cursor + N_NODES;

        zero_u32<<<(N_NODES + 255) / 256, 256, 0, stream>>>(cnt, N_NODES);
        zero_u32<<<2048, 256, 0, stream>>>((unsigned*)srt, SRT_CAP * 2);
        hist_kernel<<<2048, 256, 0, stream>>>(dst, cnt);
        scan1_kernel<<<NSCAN, 1024, 0, stream>>>(cnt, off, partials);
        scan2_kernel<<<1, 64, 0, stream>>>(partials);
        scan3_kernel<<<(N_NODES + 256) / 256, 256, 0, stream>>>(off, partials, cursor);
        scatter_sort_kernel<<<2048, 256, 0, stream>>>(src, dst, edge_w, cursor, srt);
        gemm_g_kernel<<<1563, 256, 0, stream>>>(feat, weight, g);
        pull_scalar_kernel<<<2048, 256, 0, stream>>>(g, srt, off, bias, out);
    }
}